// Round 3
// baseline (336.135 us; speedup 1.0000x reference)
//
#include <hip/hip_runtime.h>
#include <stdint.h>

#define DEV __device__ __forceinline__

typedef __attribute__((ext_vector_type(8))) short bf16x8;
typedef __attribute__((ext_vector_type(4))) float f32x4;

DEV ushort f2bf(float f) {
  union { float f; uint32_t u; } c; c.f = f;
  return (ushort)((c.u + 0x7FFFu + ((c.u >> 16) & 1)) >> 16);
}
DEV bf16x8 ld8(const ushort* p) { return *reinterpret_cast<const bf16x8*>(p); }

DEV void gload16(const void* g, void* l) {
  __builtin_amdgcn_global_load_lds(
      (const __attribute__((address_space(1))) uint32_t*)g,
      (__attribute__((address_space(3))) uint32_t*)l, 16, 0, 0);
}

// ---------------- transpose f32 [R][C] -> bf16 [C][R] ----------------
__global__ __launch_bounds__(256) void k_transpose_bf(const float* __restrict__ in,
                                                      ushort* __restrict__ out,
                                                      int R, int C) {
  __shared__ float t[32][33];
  int tx = threadIdx.x & 31, ty = threadIdx.x >> 5;
  int c0 = blockIdx.x * 32, r0 = blockIdx.y * 32;
#pragma unroll
  for (int k = 0; k < 4; ++k)
    t[ty + 8 * k][tx] = in[(size_t)(r0 + ty + 8 * k) * C + c0 + tx];
  __syncthreads();
#pragma unroll
  for (int k = 0; k < 4; ++k)
    out[(size_t)(c0 + ty + 8 * k) * R + r0 + tx] = f2bf(t[tx][ty + 8 * k]);
}

// ---------------- elementwise f32 -> bf16 ----------------
__global__ __launch_bounds__(256) void k_cvt_bf(const float* __restrict__ in,
                                                ushort* __restrict__ out, int n4) {
  int i = blockIdx.x * 256 + threadIdx.x;
  if (i >= n4) return;
  float4 v = reinterpret_cast<const float4*>(in)[i];
  ushort4 o; o.x = f2bf(v.x); o.y = f2bf(v.y); o.z = f2bf(v.z); o.w = f2bf(v.w);
  reinterpret_cast<ushort4*>(out)[i] = o;
}

// ---------------- layernorm: f32 [4096][512] -> bf16 ----------------
__global__ __launch_bounds__(64) void k_ln(const float* __restrict__ x,
                                           const float* __restrict__ g,
                                           const float* __restrict__ be,
                                           ushort* __restrict__ out) {
  int row = blockIdx.x, lane = threadIdx.x;
  const float* xr = x + (size_t)row * 512 + lane * 8;
  float4 a = *reinterpret_cast<const float4*>(xr);
  float4 b = *reinterpret_cast<const float4*>(xr + 4);
  float xs[8] = {a.x, a.y, a.z, a.w, b.x, b.y, b.z, b.w};
  float s = 0.f, q = 0.f;
#pragma unroll
  for (int i = 0; i < 8; ++i) { s += xs[i]; q += xs[i] * xs[i]; }
#pragma unroll
  for (int off = 32; off; off >>= 1) { s += __shfl_xor(s, off); q += __shfl_xor(q, off); }
  float mu = s * (1.f / 512.f);
  float var = q * (1.f / 512.f) - mu * mu;
  float inv = rsqrtf(var + 1e-5f);
  const float* gp = g + lane * 8;
  const float* bp = be + lane * 8;
  ushort o[8];
#pragma unroll
  for (int i = 0; i < 8; ++i) o[i] = f2bf((xs[i] - mu) * inv * gp[i] + bp[i]);
  *reinterpret_cast<uint4*>(out + (size_t)row * 512 + lane * 8) = *reinterpret_cast<uint4*>(o);
}

// ---------------- GEMM: C[M][N] = A[M][K] @ Bt[N][K]^T + epilogue ----------------
// EPI 0: qkv split -> q/k bf16, v^T bf16, present f32
// EPI 1: + bias + res (f32) -> outf
// EPI 2: gelu(bias+acc) -> outb (bf16)
template <int EPI>
__global__ __launch_bounds__(256) void k_gemm(
    const ushort* __restrict__ A, const ushort* __restrict__ Bt,
    int M, int N, int K,
    const float* __restrict__ bias, const float* __restrict__ res,
    float* __restrict__ outf, ushort* __restrict__ outb,
    float* __restrict__ present, ushort* __restrict__ qbf,
    ushort* __restrict__ kbf, ushort* __restrict__ vtbf) {
  __shared__ ushort As[128][64];
  __shared__ ushort Bs[128][64];
  const int tid = threadIdx.x, lane = tid & 63, w = tid >> 6;
  const int g = lane >> 4, l16 = lane & 15;
  const int m0 = blockIdx.y * 128, n0 = blockIdx.x * 128;
  const int wm = (w >> 1) * 64, wn = (w & 1) * 64;
  f32x4 acc[4][4];
#pragma unroll
  for (int i = 0; i < 4; ++i)
#pragma unroll
    for (int j = 0; j < 4; ++j) acc[i][j] = (f32x4){0.f, 0.f, 0.f, 0.f};

  const int lrow_off = (lane << 4);  // byte offset of this lane within a 1KB wave chunk
  for (int k0 = 0; k0 < K; k0 += 64) {
#pragma unroll
    for (int sw = 0; sw < 4; ++sw) {
      int offb = sw * 4096 + w * 1024;          // wave-uniform byte offset in 16KB tile
      int loff = offb + lrow_off;               // per-lane
      int row = loff >> 7, colb = loff & 127;
      gload16((const char*)A + (((size_t)(m0 + row) * K + k0) << 1) + colb,
              (char*)As + offb);
      gload16((const char*)Bt + (((size_t)(n0 + row) * K + k0) << 1) + colb,
              (char*)Bs + offb);
    }
    __syncthreads();
#pragma unroll
    for (int kk = 0; kk < 2; ++kk) {
      bf16x8 af[4], bfr[4];
#pragma unroll
      for (int f = 0; f < 4; ++f) {
        af[f] = *reinterpret_cast<const bf16x8*>(&As[wm + f * 16 + l16][kk * 32 + g * 8]);
        bfr[f] = *reinterpret_cast<const bf16x8*>(&Bs[wn + f * 16 + l16][kk * 32 + g * 8]);
      }
#pragma unroll
      for (int i = 0; i < 4; ++i)
#pragma unroll
        for (int j = 0; j < 4; ++j)
          acc[i][j] = __builtin_amdgcn_mfma_f32_16x16x32_bf16(af[i], bfr[j], acc[i][j], 0, 0, 0);
    }
    __syncthreads();
  }

#pragma unroll
  for (int i = 0; i < 4; ++i)
#pragma unroll
    for (int j = 0; j < 4; ++j)
#pragma unroll
      for (int r = 0; r < 4; ++r) {
        int row = m0 + wm + i * 16 + g * 4 + r;
        int col = n0 + wn + j * 16 + l16;
        float v = acc[i][j][r] + bias[col];
        if constexpr (EPI == 0) {
          int third = col >> 9, hh = (col >> 6) & 7, d = col & 63;
          int bb = row >> 11, sq = row & 2047;
          if (third == 0) {
            qbf[((((size_t)bb * 8 + hh) * 2048) + sq) * 64 + d] = f2bf(v);
          } else {
            present[((((size_t)bb * 2 + (third - 1)) * 8 + hh) * 2048 + sq) * 64 + d] = v;
            if (third == 1)
              kbf[((((size_t)bb * 8 + hh) * 2048) + sq) * 64 + d] = f2bf(v);
            else
              vtbf[(((size_t)bb * 8 + hh) * 64 + d) * 2048 + sq] = f2bf(v);
          }
        } else if constexpr (EPI == 1) {
          size_t idx = (size_t)row * N + col;
          outf[idx] = v + res[idx];
        } else {
          float u = 0.7978845608f * (v + 0.044715f * v * v * v);
          float e = __expf(2.f * u);
          float th = 1.f - 2.f / (e + 1.f);
          outb[(size_t)row * N + col] = f2bf(0.5f * v * (1.f + th));
        }
      }
}

// ---------------- fused causal attention, barrier-free flash ----------------
// 1024 blocks x 128 threads. Wave = one 16-row q-strip, pairs (p,127-p),
// k-tiles split even/odd across the block's 2 waves, merged once per strip.
__global__ __launch_bounds__(128) void k_attn(
    const ushort* __restrict__ qbf, const ushort* __restrict__ kbf,
    const ushort* __restrict__ vtbf, const ushort* __restrict__ Ebf,
    ushort* __restrict__ attb) {
  constexpr int S = 2048;
  __shared__ float Rs[2][16][84];
  __shared__ ushort Ps[2][16][76];
  __shared__ float Mrg[2][64][24];
  const int tid = threadIdx.x, lane = tid & 63, ks = tid >> 6;
  const int g = lane >> 4, l16 = lane & 15;
  const int bid = blockIdx.x;
  const int xcd = bid & 7, idx = bid >> 3;
  const int b = idx & 1, p = idx >> 1;
  const int h = xcd, bh = b * 8 + h;
  const ushort* qp = qbf + (size_t)bh * S * 64;
  const ushort* kp = kbf + (size_t)bh * S * 64;
  const ushort* vp = vtbf + (size_t)bh * 64 * S;
  const ushort* ep = Ebf + (size_t)h * S * 64;

  for (int si = 0; si < 2; ++si) {
    const int t = si ? (127 - p) : p;
    const int i0 = t * 16;
    bf16x8 qf[2];
    qf[0] = ld8(qp + (size_t)(i0 + l16) * 64 + g * 8);
    qf[1] = ld8(qp + (size_t)(i0 + l16) * 64 + 32 + g * 8);
    f32x4 o[4];
#pragma unroll
    for (int fv = 0; fv < 4; ++fv) o[fv] = (f32x4){0.f, 0.f, 0.f, 0.f};
    float mrun[4], lrun[4];
#pragma unroll
    for (int r = 0; r < 4; ++r) { mrun[r] = -1e30f; lrun[r] = 0.f; }
    const int nkt = t / 4 + 1;

    for (int kt = ks; kt < nkt; kt += 2) {
      const int j0 = kt * 64;
      // ---- QK^T (K fragments direct from global, L2-hot) ----
      f32x4 sacc[4];
#pragma unroll
      for (int fn = 0; fn < 4; ++fn) sacc[fn] = (f32x4){0.f, 0.f, 0.f, 0.f};
#pragma unroll
      for (int kk = 0; kk < 2; ++kk)
#pragma unroll
        for (int fn = 0; fn < 4; ++fn) {
          bf16x8 kf = ld8(kp + (size_t)(j0 + fn * 16 + l16) * 64 + kk * 32 + g * 8);
          sacc[fn] = __builtin_amdgcn_mfma_f32_16x16x32_bf16(qf[kk], kf, sacc[fn], 0, 0, 0);
        }
      // ---- relative band: q @ E[tb .. tb+79] ----
      const int tb = S - 16 - i0 + j0;
      f32x4 racc[5];
#pragma unroll
      for (int fc = 0; fc < 5; ++fc) racc[fc] = (f32x4){0.f, 0.f, 0.f, 0.f};
#pragma unroll
      for (int kk = 0; kk < 2; ++kk)
#pragma unroll
        for (int fc = 0; fc < 5; ++fc) {
          int l = tb + fc * 16 + l16; if (l > S - 1) l = S - 1;
          bf16x8 ef = ld8(ep + (size_t)l * 64 + kk * 32 + g * 8);
          racc[fc] = __builtin_amdgcn_mfma_f32_16x16x32_bf16(qf[kk], ef, racc[fc], 0, 0, 0);
        }
#pragma unroll
      for (int fc = 0; fc < 5; ++fc)
#pragma unroll
        for (int r = 0; r < 4; ++r)
          Rs[ks][g * 4 + r][fc * 16 + l16] = racc[fc][r];

      // ---- assemble S + skew gather + causal mask + online softmax ----
      float Sv[4][4], mtile[4];
#pragma unroll
      for (int r = 0; r < 4; ++r) mtile[r] = -1e30f;
#pragma unroll
      for (int fn = 0; fn < 4; ++fn)
#pragma unroll
        for (int r = 0; r < 4; ++r) {
          int dr = g * 4 + r, dj = fn * 16 + l16;
          float sv = (sacc[fn][r] + Rs[ks][dr][15 - dr + dj]) * 0.125f;
          if (j0 + dj > i0 + dr) sv = -1e30f;
          Sv[fn][r] = sv;
          mtile[r] = fmaxf(mtile[r], sv);
        }
#pragma unroll
      for (int off = 1; off < 16; off <<= 1)
#pragma unroll
        for (int r = 0; r < 4; ++r) mtile[r] = fmaxf(mtile[r], __shfl_xor(mtile[r], off));
      float corr[4], psum[4];
#pragma unroll
      for (int r = 0; r < 4; ++r) {
        float mn = fmaxf(mrun[r], mtile[r]);
        corr[r] = __expf(mrun[r] - mn);
        mrun[r] = mn;
        psum[r] = 0.f;
      }
#pragma unroll
      for (int fn = 0; fn < 4; ++fn)
#pragma unroll
        for (int r = 0; r < 4; ++r) {
          float pv = __expf(Sv[fn][r] - mrun[r]);
          psum[r] += pv;
          Ps[ks][g * 4 + r][fn * 16 + l16] = f2bf(pv);
        }
#pragma unroll
      for (int off = 1; off < 16; off <<= 1)
#pragma unroll
        for (int r = 0; r < 4; ++r) psum[r] += __shfl_xor(psum[r], off);
#pragma unroll
      for (int r = 0; r < 4; ++r) lrun[r] = lrun[r] * corr[r] + psum[r];
#pragma unroll
      for (int fv = 0; fv < 4; ++fv)
#pragma unroll
        for (int r = 0; r < 4; ++r) o[fv][r] *= corr[r];

      // ---- PV (V^T fragments direct from global) ----
#pragma unroll
      for (int kk = 0; kk < 2; ++kk) {
        bf16x8 pf = ld8(&Ps[ks][l16][kk * 32 + g * 8]);
#pragma unroll
        for (int fv = 0; fv < 4; ++fv) {
          bf16x8 vf = ld8(vp + (size_t)(fv * 16 + l16) * S + j0 + kk * 32 + g * 8);
          o[fv] = __builtin_amdgcn_mfma_f32_16x16x32_bf16(pf, vf, o[fv], 0, 0, 0);
        }
      }
    }

    // ---- merge the two k-split partials ----
    if (ks == 1) {
      float* mb = &Mrg[si][lane][0];
#pragma unroll
      for (int fv = 0; fv < 4; ++fv)
#pragma unroll
        for (int r = 0; r < 4; ++r) mb[fv * 4 + r] = o[fv][r];
#pragma unroll
      for (int r = 0; r < 4; ++r) { mb[16 + r] = mrun[r]; mb[20 + r] = lrun[r]; }
    }
    __syncthreads();
    if (ks == 0) {
      const float* mb = &Mrg[si][lane][0];
#pragma unroll
      for (int r = 0; r < 4; ++r) {
        float m1 = mb[16 + r];
        float mm = fmaxf(mrun[r], m1);
        float e0 = __expf(mrun[r] - mm), e1 = __expf(m1 - mm);
        float lc = lrun[r] * e0 + mb[20 + r] * e1;
        float inv = 1.f / lc;
#pragma unroll
        for (int fv = 0; fv < 4; ++fv) {
          float oc = o[fv][r] * e0 + mb[fv * 4 + r] * e1;
          attb[(size_t)(b * S + i0 + g * 4 + r) * 512 + h * 64 + fv * 16 + l16] =
              f2bf(oc * inv);
        }
      }
    }
  }
}

extern "C" void kernel_launch(void* const* d_in, const int* in_sizes, int n_in,
                              void* d_out, int out_size, void* d_ws, size_t ws_size,
                              hipStream_t stream) {
  const float* x = (const float*)d_in[0];
  const float* W_qkv = (const float*)d_in[2];
  const float* b_qkv = (const float*)d_in[3];
  const float* W_proj = (const float*)d_in[4];
  const float* b_proj = (const float*)d_in[5];
  const float* E = (const float*)d_in[6];
  const float* g1 = (const float*)d_in[7];
  const float* be1 = (const float*)d_in[8];
  const float* g2 = (const float*)d_in[9];
  const float* be2 = (const float*)d_in[10];
  const float* W_fc1 = (const float*)d_in[11];
  const float* b_fc1 = (const float*)d_in[12];
  const float* W_fc2 = (const float*)d_in[13];
  const float* b_fc2 = (const float*)d_in[14];

  float* x_out = (float*)d_out;                 // 2*2048*512 f32
  float* present = x_out + 2097152;             // (2,2,8,2048,64) f32

  char* ws = (char*)d_ws;
  ushort* a_bf   = (ushort*)(ws + 0);           // 4096x512 bf16
  ushort* m_bf   = (ushort*)(ws + 4194304);     // 4096x512 bf16
  ushort* q_bf   = (ushort*)(ws + 8388608);     // [b][h][s][64] bf16
  ushort* att_bf = (ushort*)(ws + 12582912);    // 4096x512 bf16
  ushort* h_bf   = (ushort*)(ws + 16777216);    // 4096x2048 bf16 (fc1 out)
  ushort* k_bf   = (ushort*)(ws + 16777216);    // aliased: [b][h][s][64] bf16 (pre-fc1)
  ushort* vt_bf  = (ushort*)(ws + 20971520);    // aliased: [b][h][64][s] bf16 (pre-fc1)
  float*  x2     = (float*)(ws + 33554432);     // 4096x512 f32
  ushort* Wqkv_t = (ushort*)(ws + 41943040);    // 1536x512 bf16
  ushort* Wproj_t= (ushort*)(ws + 43515904);    // 512x512 bf16
  ushort* Wfc1_t = (ushort*)(ws + 44040192);    // 2048x512 bf16
  ushort* Wfc2_t = (ushort*)(ws + 46137344);    // 512x2048 bf16
  ushort* E_bf   = (ushort*)(ws + 48234496);    // 8x2048x64 bf16

  k_transpose_bf<<<dim3(48, 16), 256, 0, stream>>>(W_qkv, Wqkv_t, 512, 1536);
  k_transpose_bf<<<dim3(16, 16), 256, 0, stream>>>(W_proj, Wproj_t, 512, 512);
  k_transpose_bf<<<dim3(64, 16), 256, 0, stream>>>(W_fc1, Wfc1_t, 512, 2048);
  k_transpose_bf<<<dim3(16, 64), 256, 0, stream>>>(W_fc2, Wfc2_t, 2048, 512);
  k_cvt_bf<<<1024, 256, 0, stream>>>(E, E_bf, 262144);
  k_ln<<<4096, 64, 0, stream>>>(x, g1, be1, a_bf);
  k_gemm<0><<<dim3(12, 32), 256, 0, stream>>>(a_bf, Wqkv_t, 4096, 1536, 512,
                                              b_qkv, nullptr, nullptr, nullptr,
                                              present, q_bf, k_bf, vt_bf);
  k_attn<<<1024, 128, 0, stream>>>(q_bf, k_bf, vt_bf, E_bf, att_bf);
  k_gemm<1><<<dim3(4, 32), 256, 0, stream>>>(att_bf, Wproj_t, 4096, 512, 512,
                                             b_proj, x, x2, nullptr, nullptr, nullptr,
                                             nullptr, nullptr);
  k_ln<<<4096, 64, 0, stream>>>(x2, g2, be2, m_bf);
  k_gemm<2><<<dim3(16, 32), 256, 0, stream>>>(m_bf, Wfc1_t, 4096, 2048, 512,
                                              b_fc1, nullptr, nullptr, h_bf, nullptr,
                                              nullptr, nullptr, nullptr);
  k_gemm<1><<<dim3(4, 32), 256, 0, stream>>>(h_bf, Wfc2_t, 4096, 512, 2048,
                                             b_fc2, x2, x_out, nullptr, nullptr, nullptr,
                                             nullptr, nullptr);
}

// Round 5
// 331.496 us; speedup vs baseline: 1.0140x; 1.0140x over previous
//
#include <hip/hip_runtime.h>
#include <stdint.h>

#define DEV __device__ __forceinline__

typedef __attribute__((ext_vector_type(8))) short bf16x8;
typedef __attribute__((ext_vector_type(4))) float f32x4;

DEV ushort f2bf(float f) {
  union { float f; uint32_t u; } c; c.f = f;
  return (ushort)((c.u + 0x7FFFu + ((c.u >> 16) & 1)) >> 16);
}
DEV bf16x8 ld8(const ushort* p) { return *reinterpret_cast<const bf16x8*>(p); }

DEV void gload16(const void* g, void* l) {
  __builtin_amdgcn_global_load_lds(
      (const __attribute__((address_space(1))) uint32_t*)g,
      (__attribute__((address_space(3))) uint32_t*)l, 16, 0, 0);
}

// ---------------- transpose f32 [R][C] -> bf16 [C][R] ----------------
__global__ __launch_bounds__(256) void k_transpose_bf(const float* __restrict__ in,
                                                      ushort* __restrict__ out,
                                                      int R, int C) {
  __shared__ float t[32][33];
  int tx = threadIdx.x & 31, ty = threadIdx.x >> 5;
  int c0 = blockIdx.x * 32, r0 = blockIdx.y * 32;
#pragma unroll
  for (int k = 0; k < 4; ++k)
    t[ty + 8 * k][tx] = in[(size_t)(r0 + ty + 8 * k) * C + c0 + tx];
  __syncthreads();
#pragma unroll
  for (int k = 0; k < 4; ++k)
    out[(size_t)(c0 + ty + 8 * k) * R + r0 + tx] = f2bf(t[tx][ty + 8 * k]);
}

// ---------------- elementwise f32 -> bf16 ----------------
__global__ __launch_bounds__(256) void k_cvt_bf(const float* __restrict__ in,
                                                ushort* __restrict__ out, int n4) {
  int i = blockIdx.x * 256 + threadIdx.x;
  if (i >= n4) return;
  float4 v = reinterpret_cast<const float4*>(in)[i];
  ushort4 o; o.x = f2bf(v.x); o.y = f2bf(v.y); o.z = f2bf(v.z); o.w = f2bf(v.w);
  reinterpret_cast<ushort4*>(out)[i] = o;
}

// ---------------- layernorm: f32 [4096][512] -> bf16 (4 rows/block) ----------------
__global__ __launch_bounds__(256) void k_ln(const float* __restrict__ x,
                                            const float* __restrict__ g,
                                            const float* __restrict__ be,
                                            ushort* __restrict__ out) {
  int w = threadIdx.x >> 6, lane = threadIdx.x & 63;
  int row = blockIdx.x * 4 + w;
  const float* xr = x + (size_t)row * 512 + lane * 8;
  float4 a = *reinterpret_cast<const float4*>(xr);
  float4 b = *reinterpret_cast<const float4*>(xr + 4);
  float xs[8] = {a.x, a.y, a.z, a.w, b.x, b.y, b.z, b.w};
  float s = 0.f, q = 0.f;
#pragma unroll
  for (int i = 0; i < 8; ++i) { s += xs[i]; q += xs[i] * xs[i]; }
#pragma unroll
  for (int off = 32; off; off >>= 1) { s += __shfl_xor(s, off); q += __shfl_xor(q, off); }
  float mu = s * (1.f / 512.f);
  float var = q * (1.f / 512.f) - mu * mu;
  float inv = rsqrtf(var + 1e-5f);
  const float* gp = g + lane * 8;
  const float* bp = be + lane * 8;
  ushort o[8];
#pragma unroll
  for (int i = 0; i < 8; ++i) o[i] = f2bf((xs[i] - mu) * inv * gp[i] + bp[i]);
  *reinterpret_cast<uint4*>(out + (size_t)row * 512 + lane * 8) = *reinterpret_cast<uint4*>(o);
}

// ---------------- GEMM: C[M][N] = A[M][K] @ Bt[N][K]^T + epilogue ----------------
// Tile 128 x BN (BN in {64,128}). EPI 0: qkv split; 1: +bias+res f32; 2: gelu bf16.
template <int EPI, int BN>
__global__ __launch_bounds__(256) void k_gemm(
    const ushort* __restrict__ A, const ushort* __restrict__ Bt,
    int M, int N, int K,
    const float* __restrict__ bias, const float* __restrict__ res,
    float* __restrict__ outf, ushort* __restrict__ outb,
    float* __restrict__ present, ushort* __restrict__ qbf,
    ushort* __restrict__ kbf, ushort* __restrict__ vtbf) {
  constexpr int NF = BN / 32;  // 16-col frags per wave in N
  __shared__ ushort As[128][64];
  __shared__ ushort Bs[BN][64];
  const int tid = threadIdx.x, lane = tid & 63, w = tid >> 6;
  const int g = lane >> 4, l16 = lane & 15;
  const int m0 = blockIdx.y * 128, n0 = blockIdx.x * BN;
  const int wm = (w >> 1) * 64, wn = (w & 1) * (BN / 2);
  f32x4 acc[4][NF];
#pragma unroll
  for (int i = 0; i < 4; ++i)
#pragma unroll
    for (int j = 0; j < NF; ++j) acc[i][j] = (f32x4){0.f, 0.f, 0.f, 0.f};

  const int lrow_off = (lane << 4);
  for (int k0 = 0; k0 < K; k0 += 64) {
#pragma unroll
    for (int sw = 0; sw < 4; ++sw) {
      int offb = sw * 4096 + w * 1024;
      int loff = offb + lrow_off;
      int row = loff >> 7, colb = loff & 127;
      gload16((const char*)A + (((size_t)(m0 + row) * K + k0) << 1) + colb,
              (char*)As + offb);
    }
#pragma unroll
    for (int sw = 0; sw < BN / 32; ++sw) {
      int offb = sw * 4096 + w * 1024;
      int loff = offb + lrow_off;
      int row = loff >> 7, colb = loff & 127;
      gload16((const char*)Bt + (((size_t)(n0 + row) * K + k0) << 1) + colb,
              (char*)Bs + offb);
    }
    __syncthreads();
#pragma unroll
    for (int kk = 0; kk < 2; ++kk) {
      bf16x8 af[4], bfr[NF];
#pragma unroll
      for (int f = 0; f < 4; ++f)
        af[f] = *reinterpret_cast<const bf16x8*>(&As[wm + f * 16 + l16][kk * 32 + g * 8]);
#pragma unroll
      for (int f = 0; f < NF; ++f)
        bfr[f] = *reinterpret_cast<const bf16x8*>(&Bs[wn + f * 16 + l16][kk * 32 + g * 8]);
#pragma unroll
      for (int i = 0; i < 4; ++i)
#pragma unroll
        for (int j = 0; j < NF; ++j)
          acc[i][j] = __builtin_amdgcn_mfma_f32_16x16x32_bf16(af[i], bfr[j], acc[i][j], 0, 0, 0);
    }
    __syncthreads();
  }

#pragma unroll
  for (int i = 0; i < 4; ++i)
#pragma unroll
    for (int j = 0; j < NF; ++j)
#pragma unroll
      for (int r = 0; r < 4; ++r) {
        int row = m0 + wm + i * 16 + g * 4 + r;
        int col = n0 + wn + j * 16 + l16;
        float v = acc[i][j][r] + bias[col];
        if constexpr (EPI == 0) {
          int third = col >> 9, hh = (col >> 6) & 7, d = col & 63;
          int bb = row >> 11, sq = row & 2047;
          if (third == 0) {
            qbf[((((size_t)bb * 8 + hh) * 2048) + sq) * 64 + d] = f2bf(v);
          } else {
            present[((((size_t)bb * 2 + (third - 1)) * 8 + hh) * 2048 + sq) * 64 + d] = v;
            if (third == 1)
              kbf[((((size_t)bb * 8 + hh) * 2048) + sq) * 64 + d] = f2bf(v);
            else
              vtbf[(((size_t)bb * 8 + hh) * 64 + d) * 2048 + sq] = f2bf(v);
          }
        } else if constexpr (EPI == 1) {
          size_t idx = (size_t)row * N + col;
          outf[idx] = v + res[idx];
        } else {
          float u = 0.7978845608f * (v + 0.044715f * v * v * v);
          float e = __expf(2.f * u);
          float th = 1.f - 2.f / (e + 1.f);
          outb[(size_t)row * N + col] = f2bf(0.5f * v * (1.f + th));
        }
      }
}

// ---------------- fused causal attention, latency-optimized flash ----------------
// 2048 blocks x 128 threads (2 waves). Block = one (bh, 16-row q-strip).
// k-tiles split even/odd across the 2 waves; one LDS merge at the end.
// 8 blocks/CU (15.6KB LDS), 4 waves/SIMD.
__global__ __launch_bounds__(128, 4) void k_attn(
    const ushort* __restrict__ qbf, const ushort* __restrict__ kbf,
    const ushort* __restrict__ vtbf, const ushort* __restrict__ Ebf,
    ushort* __restrict__ attb) {
  constexpr int S = 2048;
  constexpr int REG = 5376 + 2432;  // Rs[16][84]f32 + Ps[16][76]bf16 per wave
  __shared__ alignas(16) char pool[2 * REG];
  const int tid = threadIdx.x, lane = tid & 63, ks = tid >> 6;
  const int g = lane >> 4, l16 = lane & 15;
  const int bid = blockIdx.x;
  const int h = bid & 7, rest = bid >> 3;
  const int b = rest & 1, t = 127 - (rest >> 1);  // heavy strips first
  const int bh = b * 8 + h;
  float(*Rs)[84] = (float(*)[84])(pool + ks * REG);
  ushort(*Ps)[76] = (ushort(*)[76])(pool + ks * REG + 5376);
  float* Mrg = (float*)(pool + REG);  // overlays wave-1's Rs/Ps (dead at merge)

  const ushort* qp = qbf + (size_t)bh * S * 64;
  const ushort* kp = kbf + (size_t)bh * S * 64;
  const ushort* vp = vtbf + (size_t)bh * 64 * S;
  const ushort* ep = Ebf + (size_t)h * S * 64;

  const int i0 = t * 16;
  bf16x8 qf[2];
  qf[0] = ld8(qp + (size_t)(i0 + l16) * 64 + g * 8);
  qf[1] = ld8(qp + (size_t)(i0 + l16) * 64 + 32 + g * 8);
  f32x4 o[4];
#pragma unroll
  for (int fv = 0; fv < 4; ++fv) o[fv] = (f32x4){0.f, 0.f, 0.f, 0.f};
  float mrun[4], lrun[4];
#pragma unroll
  for (int r = 0; r < 4; ++r) { mrun[r] = -1e30f; lrun[r] = 0.f; }
  const int nkt = (t + 4) >> 2;

  for (int kt = ks; kt < nkt; kt += 2) {
    const int j0 = kt * 64;
    // ---- QK^T (K fragments direct from global, L2-hot) ----
    f32x4 sacc[4];
#pragma unroll
    for (int fn = 0; fn < 4; ++fn) sacc[fn] = (f32x4){0.f, 0.f, 0.f, 0.f};
#pragma unroll
    for (int kk = 0; kk < 2; ++kk)
#pragma unroll
      for (int fn = 0; fn < 4; ++fn) {
        bf16x8 kf = ld8(kp + (size_t)(j0 + fn * 16 + l16) * 64 + kk * 32 + g * 8);
        sacc[fn] = __builtin_amdgcn_mfma_f32_16x16x32_bf16(qf[kk], kf, sacc[fn], 0, 0, 0);
      }
    // ---- relative band: q @ E[tb .. tb+79] ----
    const int tb = S - 16 - i0 + j0;
    f32x4 racc[5];
#pragma unroll
    for (int fc = 0; fc < 5; ++fc) racc[fc] = (f32x4){0.f, 0.f, 0.f, 0.f};
#pragma unroll
    for (int kk = 0; kk < 2; ++kk)
#pragma unroll
      for (int fc = 0; fc < 5; ++fc) {
        int l = tb + fc * 16 + l16; if (l > S - 1) l = S - 1;
        bf16x8 ef = ld8(ep + (size_t)l * 64 + kk * 32 + g * 8);
        racc[fc] = __builtin_amdgcn_mfma_f32_16x16x32_bf16(qf[kk], ef, racc[fc], 0, 0, 0);
      }
#pragma unroll
    for (int fc = 0; fc < 5; ++fc)
#pragma unroll
      for (int r = 0; r < 4; ++r)
        Rs[g * 4 + r][fc * 16 + l16] = racc[fc][r];

    // ---- assemble S + skew gather + causal mask + online softmax ----
    float Sv[4][4], mtile[4];
#pragma unroll
    for (int r = 0; r < 4; ++r) mtile[r] = -1e30f;
#pragma unroll
    for (int fn = 0; fn < 4; ++fn)
#pragma unroll
      for (int r = 0; r < 4; ++r) {
        int dr = g * 4 + r, dj = fn * 16 + l16;
        float sv = (sacc[fn][r] + Rs[dr][15 - dr + dj]) * 0.125f;
        if (j0 + dj > i0 + dr) sv = -1e30f;
        Sv[fn][r] = sv;
        mtile[r] = fmaxf(mtile[r], sv);
      }
#pragma unroll
    for (int off = 1; off < 16; off <<= 1)
#pragma unroll
      for (int r = 0; r < 4; ++r) mtile[r] = fmaxf(mtile[r], __shfl_xor(mtile[r], off));
    float corr[4], psum[4];
#pragma unroll
    for (int r = 0; r < 4; ++r) {
      float mn = fmaxf(mrun[r], mtile[r]);
      corr[r] = __expf(mrun[r] - mn);
      mrun[r] = mn;
      psum[r] = 0.f;
    }
#pragma unroll
    for (int fn = 0; fn < 4; ++fn)
#pragma unroll
      for (int r = 0; r < 4; ++r) {
        float pv = __expf(Sv[fn][r] - mrun[r]);
        psum[r] += pv;
        Ps[g * 4 + r][fn * 16 + l16] = f2bf(pv);
      }
#pragma unroll
    for (int off = 1; off < 16; off <<= 1)
#pragma unroll
      for (int r = 0; r < 4; ++r) psum[r] += __shfl_xor(psum[r], off);
#pragma unroll
    for (int r = 0; r < 4; ++r) lrun[r] = lrun[r] * corr[r] + psum[r];
#pragma unroll
    for (int fv = 0; fv < 4; ++fv)
#pragma unroll
      for (int r = 0; r < 4; ++r) o[fv][r] *= corr[r];

    // ---- PV (V^T fragments direct from global) ----
#pragma unroll
    for (int kk = 0; kk < 2; ++kk) {
      bf16x8 pf = ld8(&Ps[l16][kk * 32 + g * 8]);
#pragma unroll
      for (int fv = 0; fv < 4; ++fv) {
        bf16x8 vf = ld8(vp + (size_t)(fv * 16 + l16) * S + j0 + kk * 32 + g * 8);
        o[fv] = __builtin_amdgcn_mfma_f32_16x16x32_bf16(pf, vf, o[fv], 0, 0, 0);
      }
    }
  }

  // ---- merge the two k-split partials ----
  if (ks == 1) {
    float* mb = Mrg + lane * 24;
#pragma unroll
    for (int fv = 0; fv < 4; ++fv)
#pragma unroll
      for (int r = 0; r < 4; ++r) mb[fv * 4 + r] = o[fv][r];
#pragma unroll
    for (int r = 0; r < 4; ++r) { mb[16 + r] = mrun[r]; mb[20 + r] = lrun[r]; }
  }
  __syncthreads();
  if (ks == 0) {
    const float* mb = Mrg + lane * 24;
#pragma unroll
    for (int r = 0; r < 4; ++r) {
      float m1 = mb[16 + r];
      float mm = fmaxf(mrun[r], m1);
      float e0 = __expf(mrun[r] - mm), e1 = __expf(m1 - mm);
      float lc = lrun[r] * e0 + mb[20 + r] * e1;
      float inv = 1.f / lc;
#pragma unroll
      for (int fv = 0; fv < 4; ++fv) {
        float oc = o[fv][r] * e0 + mb[fv * 4 + r] * e1;
        attb[(size_t)(b * S + i0 + g * 4 + r) * 512 + h * 64 + fv * 16 + l16] =
            f2bf(oc * inv);
      }
    }
  }
}

extern "C" void kernel_launch(void* const* d_in, const int* in_sizes, int n_in,
                              void* d_out, int out_size, void* d_ws, size_t ws_size,
                              hipStream_t stream) {
  const float* x = (const float*)d_in[0];
  const float* W_qkv = (const float*)d_in[2];
  const float* b_qkv = (const float*)d_in[3];
  const float* W_proj = (const float*)d_in[4];
  const float* b_proj = (const float*)d_in[5];
  const float* E = (const float*)d_in[6];
  const float* g1 = (const float*)d_in[7];
  const float* be1 = (const float*)d_in[8];
  const float* g2 = (const float*)d_in[9];
  const float* be2 = (const float*)d_in[10];
  const float* W_fc1 = (const float*)d_in[11];
  const float* b_fc1 = (const float*)d_in[12];
  const float* W_fc2 = (const float*)d_in[13];
  const float* b_fc2 = (const float*)d_in[14];

  float* x_out = (float*)d_out;                 // 2*2048*512 f32
  float* present = x_out + 2097152;             // (2,2,8,2048,64) f32

  char* ws = (char*)d_ws;
  ushort* a_bf   = (ushort*)(ws + 0);           // 4096x512 bf16
  ushort* m_bf   = (ushort*)(ws + 4194304);     // 4096x512 bf16
  ushort* q_bf   = (ushort*)(ws + 8388608);     // [b][h][s][64] bf16
  ushort* att_bf = (ushort*)(ws + 12582912);    // 4096x512 bf16
  ushort* h_bf   = (ushort*)(ws + 16777216);    // 4096x2048 bf16 (fc1 out)
  ushort* k_bf   = (ushort*)(ws + 16777216);    // aliased: [b][h][s][64] bf16 (pre-fc1)
  ushort* vt_bf  = (ushort*)(ws + 20971520);    // aliased: [b][h][64][s] bf16 (pre-fc1)
  float*  x2     = (float*)(ws + 33554432);     // 4096x512 f32
  ushort* Wqkv_t = (ushort*)(ws + 41943040);    // 1536x512 bf16
  ushort* Wproj_t= (ushort*)(ws + 43515904);    // 512x512 bf16
  ushort* Wfc1_t = (ushort*)(ws + 44040192);    // 2048x512 bf16
  ushort* Wfc2_t = (ushort*)(ws + 46137344);    // 512x2048 bf16
  ushort* E_bf   = (ushort*)(ws + 48234496);    // 8x2048x64 bf16

  k_transpose_bf<<<dim3(48, 16), 256, 0, stream>>>(W_qkv, Wqkv_t, 512, 1536);
  k_transpose_bf<<<dim3(16, 16), 256, 0, stream>>>(W_proj, Wproj_t, 512, 512);
  k_transpose_bf<<<dim3(64, 16), 256, 0, stream>>>(W_fc1, Wfc1_t, 512, 2048);
  k_transpose_bf<<<dim3(16, 64), 256, 0, stream>>>(W_fc2, Wfc2_t, 2048, 512);
  k_cvt_bf<<<1024, 256, 0, stream>>>(E, E_bf, 262144);
  k_ln<<<1024, 256, 0, stream>>>(x, g1, be1, a_bf);
  k_gemm<0, 128><<<dim3(12, 32), 256, 0, stream>>>(a_bf, Wqkv_t, 4096, 1536, 512,
                                                   b_qkv, nullptr, nullptr, nullptr,
                                                   present, q_bf, k_bf, vt_bf);
  k_attn<<<2048, 128, 0, stream>>>(q_bf, k_bf, vt_bf, E_bf, att_bf);
  k_gemm<1, 64><<<dim3(8, 32), 256, 0, stream>>>(att_bf, Wproj_t, 4096, 512, 512,
                                                 b_proj, x, x2, nullptr, nullptr, nullptr,
                                                 nullptr, nullptr);
  k_ln<<<1024, 256, 0, stream>>>(x2, g2, be2, m_bf);
  k_gemm<2, 128><<<dim3(16, 32), 256, 0, stream>>>(m_bf, Wfc1_t, 4096, 2048, 512,
                                                   b_fc1, nullptr, nullptr, h_bf, nullptr,
                                                   nullptr, nullptr, nullptr);
  k_gemm<1, 64><<<dim3(8, 32), 256, 0, stream>>>(h_bf, Wfc2_t, 4096, 512, 2048,
                                                 b_fc2, x2, x_out, nullptr, nullptr, nullptr,
                                                 nullptr, nullptr);
}

// Round 6
// 322.435 us; speedup vs baseline: 1.0425x; 1.0281x over previous
//
#include <hip/hip_runtime.h>
#include <stdint.h>

#define DEV __device__ __forceinline__

typedef __attribute__((ext_vector_type(8))) short bf16x8;
typedef __attribute__((ext_vector_type(4))) float f32x4;

DEV ushort f2bf(float f) {
  union { float f; uint32_t u; } c; c.f = f;
  return (ushort)((c.u + 0x7FFFu + ((c.u >> 16) & 1)) >> 16);
}
DEV bf16x8 ld8(const ushort* p) { return *reinterpret_cast<const bf16x8*>(p); }

DEV void gload16(const void* g, void* l) {
  __builtin_amdgcn_global_load_lds(
      (const __attribute__((address_space(1))) uint32_t*)g,
      (__attribute__((address_space(3))) uint32_t*)l, 16, 0, 0);
}

// ---------------- transpose f32 [R][C] -> bf16 [C][R] ----------------
__global__ __launch_bounds__(256) void k_transpose_bf(const float* __restrict__ in,
                                                      ushort* __restrict__ out,
                                                      int R, int C) {
  __shared__ float t[32][33];
  int tx = threadIdx.x & 31, ty = threadIdx.x >> 5;
  int c0 = blockIdx.x * 32, r0 = blockIdx.y * 32;
#pragma unroll
  for (int k = 0; k < 4; ++k)
    t[ty + 8 * k][tx] = in[(size_t)(r0 + ty + 8 * k) * C + c0 + tx];
  __syncthreads();
#pragma unroll
  for (int k = 0; k < 4; ++k)
    out[(size_t)(c0 + ty + 8 * k) * R + r0 + tx] = f2bf(t[tx][ty + 8 * k]);
}

// ---------------- elementwise f32 -> bf16 ----------------
__global__ __launch_bounds__(256) void k_cvt_bf(const float* __restrict__ in,
                                                ushort* __restrict__ out, int n4) {
  int i = blockIdx.x * 256 + threadIdx.x;
  if (i >= n4) return;
  float4 v = reinterpret_cast<const float4*>(in)[i];
  ushort4 o; o.x = f2bf(v.x); o.y = f2bf(v.y); o.z = f2bf(v.z); o.w = f2bf(v.w);
  reinterpret_cast<ushort4*>(out)[i] = o;
}

// ---------------- layernorm: f32 [4096][512] -> bf16 (4 rows/block) ----------------
__global__ __launch_bounds__(256) void k_ln(const float* __restrict__ x,
                                            const float* __restrict__ g,
                                            const float* __restrict__ be,
                                            ushort* __restrict__ out) {
  int w = threadIdx.x >> 6, lane = threadIdx.x & 63;
  int row = blockIdx.x * 4 + w;
  const float* xr = x + (size_t)row * 512 + lane * 8;
  float4 a = *reinterpret_cast<const float4*>(xr);
  float4 b = *reinterpret_cast<const float4*>(xr + 4);
  float xs[8] = {a.x, a.y, a.z, a.w, b.x, b.y, b.z, b.w};
  float s = 0.f, q = 0.f;
#pragma unroll
  for (int i = 0; i < 8; ++i) { s += xs[i]; q += xs[i] * xs[i]; }
#pragma unroll
  for (int off = 32; off; off >>= 1) { s += __shfl_xor(s, off); q += __shfl_xor(q, off); }
  float mu = s * (1.f / 512.f);
  float var = q * (1.f / 512.f) - mu * mu;
  float inv = rsqrtf(var + 1e-5f);
  const float* gp = g + lane * 8;
  const float* bp = be + lane * 8;
  ushort o[8];
#pragma unroll
  for (int i = 0; i < 8; ++i) o[i] = f2bf((xs[i] - mu) * inv * gp[i] + bp[i]);
  *reinterpret_cast<uint4*>(out + (size_t)row * 512 + lane * 8) = *reinterpret_cast<uint4*>(o);
}

// ---------------- GEMM: 2-phase double-buffered ----------------
// C[M][N] = A[M][K] @ Bt[N][K]^T. Tile 128 x BN.
// EPI 0: qkv split; 1: +bias+res f32; 2: gelu bf16.
template <int EPI, int BN>
__global__ __launch_bounds__(256) void k_gemm(
    const ushort* __restrict__ A, const ushort* __restrict__ Bt,
    int M, int N, int K,
    const float* __restrict__ bias, const float* __restrict__ res,
    float* __restrict__ outf, ushort* __restrict__ outb,
    float* __restrict__ present, ushort* __restrict__ qbf,
    ushort* __restrict__ kbf, ushort* __restrict__ vtbf) {
  constexpr int NF = BN / 32;  // 16-col frags per wave in N
  __shared__ ushort As[2][128][64];
  __shared__ ushort Bs[2][BN][64];
  const int tid = threadIdx.x, lane = tid & 63, w = tid >> 6;
  const int g = lane >> 4, l16 = lane & 15;
  const int m0 = blockIdx.y * 128, n0 = blockIdx.x * BN;
  const int wm = (w >> 1) * 64, wn = (w & 1) * (BN / 2);
  f32x4 acc[4][NF];
#pragma unroll
  for (int i = 0; i < 4; ++i)
#pragma unroll
    for (int j = 0; j < NF; ++j) acc[i][j] = (f32x4){0.f, 0.f, 0.f, 0.f};

  const int lrow_off = (lane << 4);
  auto stage = [&](int buf, int k0) {
#pragma unroll
    for (int sw = 0; sw < 4; ++sw) {
      int offb = sw * 4096 + w * 1024;
      int loff = offb + lrow_off;
      int row = loff >> 7, colb = loff & 127;
      gload16((const char*)A + (((size_t)(m0 + row) * K + k0) << 1) + colb,
              (char*)(&As[buf][0][0]) + offb);
    }
#pragma unroll
    for (int sw = 0; sw < BN / 32; ++sw) {
      int offb = sw * 4096 + w * 1024;
      int loff = offb + lrow_off;
      int row = loff >> 7, colb = loff & 127;
      gload16((const char*)Bt + (((size_t)(n0 + row) * K + k0) << 1) + colb,
              (char*)(&Bs[buf][0][0]) + offb);
    }
  };

  const int nt = K >> 6;
  stage(0, 0);
  __syncthreads();  // drains vmcnt(0): buf0 ready
  for (int t = 0; t < nt; ++t) {
    const int cur = t & 1;
    if (t + 1 < nt) stage(cur ^ 1, (t + 1) << 6);  // async prefetch next tile
#pragma unroll
    for (int kk = 0; kk < 2; ++kk) {
      bf16x8 af[4], bfr[NF];
#pragma unroll
      for (int f = 0; f < 4; ++f)
        af[f] = *reinterpret_cast<const bf16x8*>(&As[cur][wm + f * 16 + l16][kk * 32 + g * 8]);
#pragma unroll
      for (int f = 0; f < NF; ++f)
        bfr[f] = *reinterpret_cast<const bf16x8*>(&Bs[cur][wn + f * 16 + l16][kk * 32 + g * 8]);
#pragma unroll
      for (int i = 0; i < 4; ++i)
#pragma unroll
        for (int j = 0; j < NF; ++j)
          acc[i][j] = __builtin_amdgcn_mfma_f32_16x16x32_bf16(af[i], bfr[j], acc[i][j], 0, 0, 0);
    }
    __syncthreads();  // one barrier/step: drains next-tile vmcnt + our lgkm
  }

#pragma unroll
  for (int i = 0; i < 4; ++i)
#pragma unroll
    for (int j = 0; j < NF; ++j)
#pragma unroll
      for (int r = 0; r < 4; ++r) {
        int row = m0 + wm + i * 16 + g * 4 + r;
        int col = n0 + wn + j * 16 + l16;
        float v = acc[i][j][r] + bias[col];
        if constexpr (EPI == 0) {
          int third = col >> 9, hh = (col >> 6) & 7, d = col & 63;
          int bb = row >> 11, sq = row & 2047;
          if (third == 0) {
            qbf[((((size_t)bb * 8 + hh) * 2048) + sq) * 64 + d] = f2bf(v);
          } else {
            present[((((size_t)bb * 2 + (third - 1)) * 8 + hh) * 2048 + sq) * 64 + d] = v;
            if (third == 1)
              kbf[((((size_t)bb * 8 + hh) * 2048) + sq) * 64 + d] = f2bf(v);
            else
              vtbf[(((size_t)bb * 8 + hh) * 64 + d) * 2048 + sq] = f2bf(v);
          }
        } else if constexpr (EPI == 1) {
          size_t idx = (size_t)row * N + col;
          outf[idx] = v + res[idx];
        } else {
          float u = 0.7978845608f * (v + 0.044715f * v * v * v);
          float e = __expf(2.f * u);
          float th = 1.f - 2.f / (e + 1.f);
          outb[(size_t)row * N + col] = f2bf(0.5f * v * (1.f + th));
        }
      }
}

// ---------------- fused causal attention, batched-load flash ----------------
// 2048 blocks x 128 threads (2 waves). Block = one (bh, 16-row q-strip).
// All 26 loads of a k-tile issued up front into registers (one L2 latency per
// iteration); skew gather via in-wave shuffle (no Rs LDS).
__global__ __launch_bounds__(128, 2) void k_attn(
    const ushort* __restrict__ qbf, const ushort* __restrict__ kbf,
    const ushort* __restrict__ vtbf, const ushort* __restrict__ Ebf,
    ushort* __restrict__ attb) {
  constexpr int S = 2048;
  __shared__ ushort Ps[2][16][76];
  __shared__ float Mrg[64][24];
  const int tid = threadIdx.x, lane = tid & 63, ks = tid >> 6;
  const int g = lane >> 4, l16 = lane & 15;
  const int bid = blockIdx.x;
  const int h = bid & 7, rest = bid >> 3;
  const int b = rest & 1, t = 127 - (rest >> 1);  // heavy strips first
  const int bh = b * 8 + h;

  const ushort* qp = qbf + (size_t)bh * S * 64;
  const ushort* kp = kbf + (size_t)bh * S * 64;
  const ushort* vp = vtbf + (size_t)bh * 64 * S;
  const ushort* ep = Ebf + (size_t)h * S * 64;

  const int i0 = t * 16;
  bf16x8 qf[2];
  qf[0] = ld8(qp + (size_t)(i0 + l16) * 64 + g * 8);
  qf[1] = ld8(qp + (size_t)(i0 + l16) * 64 + 32 + g * 8);
  f32x4 o[4];
#pragma unroll
  for (int fv = 0; fv < 4; ++fv) o[fv] = (f32x4){0.f, 0.f, 0.f, 0.f};
  float mrun[4], lrun[4];
#pragma unroll
  for (int r = 0; r < 4; ++r) { mrun[r] = -1e30f; lrun[r] = 0.f; }
  const int nkt = (t + 4) >> 2;

  for (int kt = ks; kt < nkt; kt += 2) {
    const int j0 = kt * 64;
    const int tb = S - 16 - i0 + j0;
    // ---- issue ALL loads for this k-tile up front ----
    bf16x8 kf[8], ef[10], vf[8];
#pragma unroll
    for (int fn = 0; fn < 4; ++fn) {
      const ushort* kr = kp + (size_t)(j0 + fn * 16 + l16) * 64 + g * 8;
      kf[fn] = ld8(kr);
      kf[4 + fn] = ld8(kr + 32);
    }
#pragma unroll
    for (int fc = 0; fc < 5; ++fc) {
      int l = tb + fc * 16 + l16; if (l > S - 1) l = S - 1;
      const ushort* er = ep + (size_t)l * 64 + g * 8;
      ef[fc] = ld8(er);
      ef[5 + fc] = ld8(er + 32);
    }
#pragma unroll
    for (int fv = 0; fv < 4; ++fv) {
      const ushort* vr = vp + (size_t)(fv * 16 + l16) * S + j0 + g * 8;
      vf[fv] = ld8(vr);
      vf[4 + fv] = ld8(vr + 32);
    }

    // ---- QK^T ----
    f32x4 sacc[4];
#pragma unroll
    for (int fn = 0; fn < 4; ++fn) sacc[fn] = (f32x4){0.f, 0.f, 0.f, 0.f};
#pragma unroll
    for (int kk = 0; kk < 2; ++kk)
#pragma unroll
      for (int fn = 0; fn < 4; ++fn)
        sacc[fn] = __builtin_amdgcn_mfma_f32_16x16x32_bf16(qf[kk], kf[kk * 4 + fn], sacc[fn], 0, 0, 0);

    // ---- relative band: q @ E[tb .. tb+79] ----
    f32x4 racc[5];
#pragma unroll
    for (int fc = 0; fc < 5; ++fc) racc[fc] = (f32x4){0.f, 0.f, 0.f, 0.f};
#pragma unroll
    for (int kk = 0; kk < 2; ++kk)
#pragma unroll
      for (int fc = 0; fc < 5; ++fc)
        racc[fc] = __builtin_amdgcn_mfma_f32_16x16x32_bf16(qf[kk], ef[kk * 5 + fc], racc[fc], 0, 0, 0);

    // ---- skew gather via in-wave shuffle + mask + online softmax ----
    // rel[dr][b], b = 15-dr+dj lives at lane (g, b&15) reg (fn + (l16>dr), r).
    float Sv[4][4], mtile[4];
#pragma unroll
    for (int r = 0; r < 4; ++r) mtile[r] = -1e30f;
#pragma unroll
    for (int r = 0; r < 4; ++r) {
      const int dr = g * 4 + r;
      const int src = (lane & 48) | ((l16 + 15 - dr) & 15);
      const bool hi = (l16 > dr);
#pragma unroll
      for (int fn = 0; fn < 4; ++fn) {
        float lo_v = __shfl(racc[fn][r], src);
        float hi_v = __shfl(racc[fn + 1][r], src);
        float rel = hi ? hi_v : lo_v;
        float sv = (sacc[fn][r] + rel) * 0.125f;
        int dj = fn * 16 + l16;
        if (j0 + dj > i0 + dr) sv = -1e30f;
        Sv[fn][r] = sv;
        mtile[r] = fmaxf(mtile[r], sv);
      }
    }
#pragma unroll
    for (int off = 1; off < 16; off <<= 1)
#pragma unroll
      for (int r = 0; r < 4; ++r) mtile[r] = fmaxf(mtile[r], __shfl_xor(mtile[r], off));
    float corr[4], psum[4];
#pragma unroll
    for (int r = 0; r < 4; ++r) {
      float mn = fmaxf(mrun[r], mtile[r]);
      corr[r] = __expf(mrun[r] - mn);
      mrun[r] = mn;
      psum[r] = 0.f;
    }
#pragma unroll
    for (int fn = 0; fn < 4; ++fn)
#pragma unroll
      for (int r = 0; r < 4; ++r) {
        float pv = __expf(Sv[fn][r] - mrun[r]);
        psum[r] += pv;
        Ps[ks][g * 4 + r][fn * 16 + l16] = f2bf(pv);
      }
#pragma unroll
    for (int off = 1; off < 16; off <<= 1)
#pragma unroll
      for (int r = 0; r < 4; ++r) psum[r] += __shfl_xor(psum[r], off);
#pragma unroll
    for (int r = 0; r < 4; ++r) lrun[r] = lrun[r] * corr[r] + psum[r];
#pragma unroll
    for (int fv = 0; fv < 4; ++fv)
#pragma unroll
      for (int r = 0; r < 4; ++r) o[fv][r] *= corr[r];

    // ---- PV (V^T from prefetched regs) ----
#pragma unroll
    for (int kk = 0; kk < 2; ++kk) {
      bf16x8 pf = ld8(&Ps[ks][l16][kk * 32 + g * 8]);
#pragma unroll
      for (int fv = 0; fv < 4; ++fv)
        o[fv] = __builtin_amdgcn_mfma_f32_16x16x32_bf16(pf, vf[kk * 4 + fv], o[fv], 0, 0, 0);
    }
  }

  // ---- merge the two k-split partials ----
  if (ks == 1) {
    float* mb = &Mrg[lane][0];
#pragma unroll
    for (int fv = 0; fv < 4; ++fv)
#pragma unroll
      for (int r = 0; r < 4; ++r) mb[fv * 4 + r] = o[fv][r];
#pragma unroll
    for (int r = 0; r < 4; ++r) { mb[16 + r] = mrun[r]; mb[20 + r] = lrun[r]; }
  }
  __syncthreads();
  if (ks == 0) {
    const float* mb = &Mrg[lane][0];
#pragma unroll
    for (int r = 0; r < 4; ++r) {
      float m1 = mb[16 + r];
      float mm = fmaxf(mrun[r], m1);
      float e0 = __expf(mrun[r] - mm), e1 = __expf(m1 - mm);
      float lc = lrun[r] * e0 + mb[20 + r] * e1;
      float inv = 1.f / lc;
#pragma unroll
      for (int fv = 0; fv < 4; ++fv) {
        float oc = o[fv][r] * e0 + mb[fv * 4 + r] * e1;
        attb[(size_t)(b * S + i0 + g * 4 + r) * 512 + h * 64 + fv * 16 + l16] =
            f2bf(oc * inv);
      }
    }
  }
}

extern "C" void kernel_launch(void* const* d_in, const int* in_sizes, int n_in,
                              void* d_out, int out_size, void* d_ws, size_t ws_size,
                              hipStream_t stream) {
  const float* x = (const float*)d_in[0];
  const float* W_qkv = (const float*)d_in[2];
  const float* b_qkv = (const float*)d_in[3];
  const float* W_proj = (const float*)d_in[4];
  const float* b_proj = (const float*)d_in[5];
  const float* E = (const float*)d_in[6];
  const float* g1 = (const float*)d_in[7];
  const float* be1 = (const float*)d_in[8];
  const float* g2 = (const float*)d_in[9];
  const float* be2 = (const float*)d_in[10];
  const float* W_fc1 = (const float*)d_in[11];
  const float* b_fc1 = (const float*)d_in[12];
  const float* W_fc2 = (const float*)d_in[13];
  const float* b_fc2 = (const float*)d_in[14];

  float* x_out = (float*)d_out;                 // 2*2048*512 f32
  float* present = x_out + 2097152;             // (2,2,8,2048,64) f32

  char* ws = (char*)d_ws;
  ushort* a_bf   = (ushort*)(ws + 0);           // 4096x512 bf16
  ushort* m_bf   = (ushort*)(ws + 4194304);     // 4096x512 bf16
  ushort* q_bf   = (ushort*)(ws + 8388608);     // [b][h][s][64] bf16
  ushort* att_bf = (ushort*)(ws + 12582912);    // 4096x512 bf16
  ushort* h_bf   = (ushort*)(ws + 16777216);    // 4096x2048 bf16 (fc1 out)
  ushort* k_bf   = (ushort*)(ws + 16777216);    // aliased: [b][h][s][64] bf16 (pre-fc1)
  ushort* vt_bf  = (ushort*)(ws + 20971520);    // aliased: [b][h][64][s] bf16 (pre-fc1)
  float*  x2     = (float*)(ws + 33554432);     // 4096x512 f32
  ushort* Wqkv_t = (ushort*)(ws + 41943040);    // 1536x512 bf16
  ushort* Wproj_t= (ushort*)(ws + 43515904);    // 512x512 bf16
  ushort* Wfc1_t = (ushort*)(ws + 44040192);    // 2048x512 bf16
  ushort* Wfc2_t = (ushort*)(ws + 46137344);    // 512x2048 bf16
  ushort* E_bf   = (ushort*)(ws + 48234496);    // 8x2048x64 bf16

  k_transpose_bf<<<dim3(48, 16), 256, 0, stream>>>(W_qkv, Wqkv_t, 512, 1536);
  k_transpose_bf<<<dim3(16, 16), 256, 0, stream>>>(W_proj, Wproj_t, 512, 512);
  k_transpose_bf<<<dim3(64, 16), 256, 0, stream>>>(W_fc1, Wfc1_t, 512, 2048);
  k_transpose_bf<<<dim3(16, 64), 256, 0, stream>>>(W_fc2, Wfc2_t, 2048, 512);
  k_cvt_bf<<<1024, 256, 0, stream>>>(E, E_bf, 262144);
  k_ln<<<1024, 256, 0, stream>>>(x, g1, be1, a_bf);
  k_gemm<0, 128><<<dim3(12, 32), 256, 0, stream>>>(a_bf, Wqkv_t, 4096, 1536, 512,
                                                   b_qkv, nullptr, nullptr, nullptr,
                                                   present, q_bf, k_bf, vt_bf);
  k_attn<<<2048, 128, 0, stream>>>(q_bf, k_bf, vt_bf, E_bf, att_bf);
  k_gemm<1, 64><<<dim3(8, 32), 256, 0, stream>>>(att_bf, Wproj_t, 4096, 512, 512,
                                                 b_proj, x, x2, nullptr, nullptr, nullptr,
                                                 nullptr, nullptr);
  k_ln<<<1024, 256, 0, stream>>>(x2, g2, be2, m_bf);
  k_gemm<2, 128><<<dim3(16, 32), 256, 0, stream>>>(m_bf, Wfc1_t, 4096, 2048, 512,
                                                   b_fc1, nullptr, nullptr, h_bf, nullptr,
                                                   nullptr, nullptr, nullptr);
  k_gemm<1, 64><<<dim3(8, 32), 256, 0, stream>>>(h_bf, Wfc2_t, 4096, 512, 2048,
                                                 b_fc2, x2, x_out, nullptr, nullptr, nullptr,
                                                 nullptr, nullptr);
}

// Round 7
// 312.072 us; speedup vs baseline: 1.0771x; 1.0332x over previous
//
#include <hip/hip_runtime.h>
#include <stdint.h>

#define DEV __device__ __forceinline__
#define SCHEDB __builtin_amdgcn_sched_barrier(0)
#define WAITVM(n) asm volatile("s_waitcnt vmcnt(" #n ")" ::: "memory")
#define WAITLG asm volatile("s_waitcnt lgkmcnt(0)" ::: "memory")

typedef __attribute__((ext_vector_type(8))) short bf16x8;
typedef __attribute__((ext_vector_type(4))) float f32x4;

DEV ushort f2bf(float f) {
  union { float f; uint32_t u; } c; c.f = f;
  return (ushort)((c.u + 0x7FFFu + ((c.u >> 16) & 1)) >> 16);
}
DEV bf16x8 ld8(const ushort* p) { return *reinterpret_cast<const bf16x8*>(p); }

DEV void gload16(const void* g, void* l) {
  __builtin_amdgcn_global_load_lds(
      (const __attribute__((address_space(1))) uint32_t*)g,
      (__attribute__((address_space(3))) uint32_t*)l, 16, 0, 0);
}

// ---------------- transpose f32 [R][C] -> bf16 [C][R] ----------------
__global__ __launch_bounds__(256) void k_transpose_bf(const float* __restrict__ in,
                                                      ushort* __restrict__ out,
                                                      int R, int C) {
  __shared__ float t[32][33];
  int tx = threadIdx.x & 31, ty = threadIdx.x >> 5;
  int c0 = blockIdx.x * 32, r0 = blockIdx.y * 32;
#pragma unroll
  for (int k = 0; k < 4; ++k)
    t[ty + 8 * k][tx] = in[(size_t)(r0 + ty + 8 * k) * C + c0 + tx];
  __syncthreads();
#pragma unroll
  for (int k = 0; k < 4; ++k)
    out[(size_t)(c0 + ty + 8 * k) * R + r0 + tx] = f2bf(t[tx][ty + 8 * k]);
}

// ---------------- elementwise f32 -> bf16 ----------------
__global__ __launch_bounds__(256) void k_cvt_bf(const float* __restrict__ in,
                                                ushort* __restrict__ out, int n4) {
  int i = blockIdx.x * 256 + threadIdx.x;
  if (i >= n4) return;
  float4 v = reinterpret_cast<const float4*>(in)[i];
  ushort4 o; o.x = f2bf(v.x); o.y = f2bf(v.y); o.z = f2bf(v.z); o.w = f2bf(v.w);
  reinterpret_cast<ushort4*>(out)[i] = o;
}

// ---------------- layernorm: f32 [4096][512] -> bf16 (4 rows/block) ----------------
__global__ __launch_bounds__(256) void k_ln(const float* __restrict__ x,
                                            const float* __restrict__ g,
                                            const float* __restrict__ be,
                                            ushort* __restrict__ out) {
  int w = threadIdx.x >> 6, lane = threadIdx.x & 63;
  int row = blockIdx.x * 4 + w;
  const float* xr = x + (size_t)row * 512 + lane * 8;
  float4 a = *reinterpret_cast<const float4*>(xr);
  float4 b = *reinterpret_cast<const float4*>(xr + 4);
  float xs[8] = {a.x, a.y, a.z, a.w, b.x, b.y, b.z, b.w};
  float s = 0.f, q = 0.f;
#pragma unroll
  for (int i = 0; i < 8; ++i) { s += xs[i]; q += xs[i] * xs[i]; }
#pragma unroll
  for (int off = 32; off; off >>= 1) { s += __shfl_xor(s, off); q += __shfl_xor(q, off); }
  float mu = s * (1.f / 512.f);
  float var = q * (1.f / 512.f) - mu * mu;
  float inv = rsqrtf(var + 1e-5f);
  const float* gp = g + lane * 8;
  const float* bp = be + lane * 8;
  ushort o[8];
#pragma unroll
  for (int i = 0; i < 8; ++i) o[i] = f2bf((xs[i] - mu) * inv * gp[i] + bp[i]);
  *reinterpret_cast<uint4*>(out + (size_t)row * 512 + lane * 8) = *reinterpret_cast<uint4*>(o);
}

// ---------------- GEMM: counted-vmcnt 2-phase double-buffered ----------------
// C[M][N] = A[M][K] @ Bt[N][K]^T. Tile 128 x BN.
// Prefetch of tile t+2 stays in flight across barriers (vmcnt(LOADS), never 0
// mid-loop). EPI 0: qkv split; 1: +bias+res f32; 2: gelu bf16.
template <int EPI, int BN>
__global__ __launch_bounds__(256) void k_gemm(
    const ushort* __restrict__ A, const ushort* __restrict__ Bt,
    int M, int N, int K,
    const float* __restrict__ bias, const float* __restrict__ res,
    float* __restrict__ outf, ushort* __restrict__ outb,
    float* __restrict__ present, ushort* __restrict__ qbf,
    ushort* __restrict__ kbf, ushort* __restrict__ vtbf) {
  constexpr int NF = BN / 32;        // 16-col frags per wave in N
  constexpr int LOADS = 4 + BN / 32; // gload_lds per thread per stage
  __shared__ ushort As[2][128][64];
  __shared__ ushort Bs[2][BN][64];
  const int tid = threadIdx.x, lane = tid & 63, w = tid >> 6;
  const int g = lane >> 4, l16 = lane & 15;
  const int m0 = blockIdx.y * 128, n0 = blockIdx.x * BN;
  const int wm = (w >> 1) * 64, wn = (w & 1) * (BN / 2);
  f32x4 acc[4][NF];
#pragma unroll
  for (int i = 0; i < 4; ++i)
#pragma unroll
    for (int j = 0; j < NF; ++j) acc[i][j] = (f32x4){0.f, 0.f, 0.f, 0.f};

  const int lrow_off = (lane << 4);
  auto stage = [&](int buf, int k0) {
#pragma unroll
    for (int sw = 0; sw < 4; ++sw) {
      int offb = sw * 4096 + w * 1024;
      int loff = offb + lrow_off;
      int row = loff >> 7, colb = loff & 127;
      gload16((const char*)A + (((size_t)(m0 + row) * K + k0) << 1) + colb,
              (char*)(&As[buf][0][0]) + offb);
    }
#pragma unroll
    for (int sw = 0; sw < BN / 32; ++sw) {
      int offb = sw * 4096 + w * 1024;
      int loff = offb + lrow_off;
      int row = loff >> 7, colb = loff & 127;
      gload16((const char*)Bt + (((size_t)(n0 + row) * K + k0) << 1) + colb,
              (char*)(&Bs[buf][0][0]) + offb);
    }
  };

  const int nt = K >> 6;  // >= 8 for all our shapes
  stage(0, 0);
  stage(1, 64);
  if constexpr (LOADS == 8) WAITVM(8); else WAITVM(6);  // buf0 landed (mine)
  SCHEDB;
  __builtin_amdgcn_s_barrier();  // buf0 landed (all waves)
  SCHEDB;

  for (int t = 0; t < nt; ++t) {
    const int cur = t & 1;
    bf16x8 af[2][4], bfr[2][NF];
#pragma unroll
    for (int kk = 0; kk < 2; ++kk) {
#pragma unroll
      for (int f = 0; f < 4; ++f)
        af[kk][f] = *reinterpret_cast<const bf16x8*>(
            &As[cur][wm + f * 16 + l16][kk * 32 + g * 8]);
#pragma unroll
      for (int f = 0; f < NF; ++f)
        bfr[kk][f] = *reinterpret_cast<const bf16x8*>(
            &Bs[cur][wn + f * 16 + l16][kk * 32 + g * 8]);
    }
    WAITLG;   // my reads of buf[cur] complete
    SCHEDB;
    __builtin_amdgcn_s_barrier();  // B1: ALL waves done reading buf[cur]
    SCHEDB;
    if (t + 2 < nt) stage(cur, (t + 2) << 6);  // overwrite buf[cur], async
    SCHEDB;   // pin: stage issued before MFMAs (static order for vmcnt count)
#pragma unroll
    for (int kk = 0; kk < 2; ++kk)
#pragma unroll
      for (int i = 0; i < 4; ++i)
#pragma unroll
        for (int j = 0; j < NF; ++j)
          acc[i][j] = __builtin_amdgcn_mfma_f32_16x16x32_bf16(
              af[kk][i], bfr[kk][j], acc[i][j], 0, 0, 0);
    SCHEDB;
    if (t + 1 < nt) {
      if (t + 2 < nt) {
        if constexpr (LOADS == 8) WAITVM(8); else WAITVM(6);  // buf[t+1] done, t+2 in flight
      } else {
        WAITVM(0);  // tail: drain last tile
      }
      SCHEDB;
      __builtin_amdgcn_s_barrier();  // B2: buf[t+1] ready everywhere
      SCHEDB;
    }
  }

#pragma unroll
  for (int i = 0; i < 4; ++i)
#pragma unroll
    for (int j = 0; j < NF; ++j)
#pragma unroll
      for (int r = 0; r < 4; ++r) {
        int row = m0 + wm + i * 16 + g * 4 + r;
        int col = n0 + wn + j * 16 + l16;
        float v = acc[i][j][r] + bias[col];
        if constexpr (EPI == 0) {
          int third = col >> 9, hh = (col >> 6) & 7, d = col & 63;
          int bb = row >> 11, sq = row & 2047;
          if (third == 0) {
            qbf[((((size_t)bb * 8 + hh) * 2048) + sq) * 64 + d] = f2bf(v);
          } else {
            present[((((size_t)bb * 2 + (third - 1)) * 8 + hh) * 2048 + sq) * 64 + d] = v;
            if (third == 1)
              kbf[((((size_t)bb * 8 + hh) * 2048) + sq) * 64 + d] = f2bf(v);
            else
              vtbf[(((size_t)bb * 8 + hh) * 64 + d) * 2048 + sq] = f2bf(v);
          }
        } else if constexpr (EPI == 1) {
          size_t idx = (size_t)row * N + col;
          outf[idx] = v + res[idx];
        } else {
          float u = 0.7978845608f * (v + 0.044715f * v * v * v);
          float e = __expf(2.f * u);
          float th = 1.f - 2.f / (e + 1.f);
          outb[(size_t)row * N + col] = f2bf(0.5f * v * (1.f + th));
        }
      }
}

// ---------------- fused causal attention, batch-issued loads ----------------
// 2048 blocks x 128 threads (2 waves). Block = one (bh, 16-row q-strip).
// sched_barrier(0) pins all 26 loads of a k-tile to issue BEFORE any consumer
// -> one L2 latency per iteration. Skew gather via in-wave shuffle.
__global__ __launch_bounds__(128, 2) void k_attn(
    const ushort* __restrict__ qbf, const ushort* __restrict__ kbf,
    const ushort* __restrict__ vtbf, const ushort* __restrict__ Ebf,
    ushort* __restrict__ attb) {
  constexpr int S = 2048;
  __shared__ ushort Ps[2][16][76];
  __shared__ float Mrg[64][24];
  const int tid = threadIdx.x, lane = tid & 63, ks = tid >> 6;
  const int g = lane >> 4, l16 = lane & 15;
  const int bid = blockIdx.x;
  const int h = bid & 7, rest = bid >> 3;
  const int b = rest & 1, t = 127 - (rest >> 1);  // heavy strips first
  const int bh = b * 8 + h;

  const ushort* qp = qbf + (size_t)bh * S * 64;
  const ushort* kp = kbf + (size_t)bh * S * 64;
  const ushort* vp = vtbf + (size_t)bh * 64 * S;
  const ushort* ep = Ebf + (size_t)h * S * 64;

  const int i0 = t * 16;
  bf16x8 qf[2];
  qf[0] = ld8(qp + (size_t)(i0 + l16) * 64 + g * 8);
  qf[1] = ld8(qp + (size_t)(i0 + l16) * 64 + 32 + g * 8);
  f32x4 o[4];
#pragma unroll
  for (int fv = 0; fv < 4; ++fv) o[fv] = (f32x4){0.f, 0.f, 0.f, 0.f};
  float mrun[4], lrun[4];
#pragma unroll
  for (int r = 0; r < 4; ++r) { mrun[r] = -1e30f; lrun[r] = 0.f; }
  const int nkt = (t + 4) >> 2;

  for (int kt = ks; kt < nkt; kt += 2) {
    const int j0 = kt * 64;
    const int tb = S - 16 - i0 + j0;
    // ---- issue ALL loads for this k-tile, then fence issue order ----
    bf16x8 kf[8], ef[10], vf[8];
#pragma unroll
    for (int fn = 0; fn < 4; ++fn) {
      const ushort* kr = kp + (size_t)(j0 + fn * 16 + l16) * 64 + g * 8;
      kf[fn] = ld8(kr);
      kf[4 + fn] = ld8(kr + 32);
    }
#pragma unroll
    for (int fc = 0; fc < 5; ++fc) {
      int l = tb + fc * 16 + l16; if (l > S - 1) l = S - 1;
      const ushort* er = ep + (size_t)l * 64 + g * 8;
      ef[fc] = ld8(er);
      ef[5 + fc] = ld8(er + 32);
    }
#pragma unroll
    for (int fv = 0; fv < 4; ++fv) {
      const ushort* vr = vp + (size_t)(fv * 16 + l16) * S + j0 + g * 8;
      vf[fv] = ld8(vr);
      vf[4 + fv] = ld8(vr + 32);
    }
    SCHEDB;  // all 26 loads issued before any consumer (one latency window)

    // ---- QK^T ----
    f32x4 sacc[4];
#pragma unroll
    for (int fn = 0; fn < 4; ++fn) sacc[fn] = (f32x4){0.f, 0.f, 0.f, 0.f};
#pragma unroll
    for (int kk = 0; kk < 2; ++kk)
#pragma unroll
      for (int fn = 0; fn < 4; ++fn)
        sacc[fn] = __builtin_amdgcn_mfma_f32_16x16x32_bf16(qf[kk], kf[kk * 4 + fn], sacc[fn], 0, 0, 0);

    // ---- relative band: q @ E[tb .. tb+79] ----
    f32x4 racc[5];
#pragma unroll
    for (int fc = 0; fc < 5; ++fc) racc[fc] = (f32x4){0.f, 0.f, 0.f, 0.f};
#pragma unroll
    for (int kk = 0; kk < 2; ++kk)
#pragma unroll
      for (int fc = 0; fc < 5; ++fc)
        racc[fc] = __builtin_amdgcn_mfma_f32_16x16x32_bf16(qf[kk], ef[kk * 5 + fc], racc[fc], 0, 0, 0);

    // ---- skew gather via in-wave shuffle + mask + online softmax ----
    float Sv[4][4], mtile[4];
#pragma unroll
    for (int r = 0; r < 4; ++r) mtile[r] = -1e30f;
#pragma unroll
    for (int r = 0; r < 4; ++r) {
      const int dr = g * 4 + r;
      const int src = (lane & 48) | ((l16 + 15 - dr) & 15);
      const bool hi = (l16 > dr);
#pragma unroll
      for (int fn = 0; fn < 4; ++fn) {
        float lo_v = __shfl(racc[fn][r], src);
        float hi_v = __shfl(racc[fn + 1][r], src);
        float rel = hi ? hi_v : lo_v;
        float sv = (sacc[fn][r] + rel) * 0.125f;
        int dj = fn * 16 + l16;
        if (j0 + dj > i0 + dr) sv = -1e30f;
        Sv[fn][r] = sv;
        mtile[r] = fmaxf(mtile[r], sv);
      }
    }
#pragma unroll
    for (int off = 1; off < 16; off <<= 1)
#pragma unroll
      for (int r = 0; r < 4; ++r) mtile[r] = fmaxf(mtile[r], __shfl_xor(mtile[r], off));
    float corr[4], psum[4];
#pragma unroll
    for (int r = 0; r < 4; ++r) {
      float mn = fmaxf(mrun[r], mtile[r]);
      corr[r] = __expf(mrun[r] - mn);
      mrun[r] = mn;
      psum[r] = 0.f;
    }
#pragma unroll
    for (int fn = 0; fn < 4; ++fn)
#pragma unroll
      for (int r = 0; r < 4; ++r) {
        float pv = __expf(Sv[fn][r] - mrun[r]);
        psum[r] += pv;
        Ps[ks][g * 4 + r][fn * 16 + l16] = f2bf(pv);
      }
#pragma unroll
    for (int off = 1; off < 16; off <<= 1)
#pragma unroll
      for (int r = 0; r < 4; ++r) psum[r] += __shfl_xor(psum[r], off);
#pragma unroll
    for (int r = 0; r < 4; ++r) lrun[r] = lrun[r] * corr[r] + psum[r];
#pragma unroll
    for (int fv = 0; fv < 4; ++fv)
#pragma unroll
      for (int r = 0; r < 4; ++r) o[fv][r] *= corr[r];

    // ---- PV (V^T from prefetched regs) ----
#pragma unroll
    for (int kk = 0; kk < 2; ++kk) {
      bf16x8 pf = ld8(&Ps[ks][l16][kk * 32 + g * 8]);
#pragma unroll
      for (int fv = 0; fv < 4; ++fv)
        o[fv] = __builtin_amdgcn_mfma_f32_16x16x32_bf16(pf, vf[kk * 4 + fv], o[fv], 0, 0, 0);
    }
  }

  // ---- merge the two k-split partials ----
  if (ks == 1) {
    float* mb = &Mrg[lane][0];
#pragma unroll
    for (int fv = 0; fv < 4; ++fv)
#pragma unroll
      for (int r = 0; r < 4; ++r) mb[fv * 4 + r] = o[fv][r];
#pragma unroll
    for (int r = 0; r < 4; ++r) { mb[16 + r] = mrun[r]; mb[20 + r] = lrun[r]; }
  }
  __syncthreads();
  if (ks == 0) {
    const float* mb = &Mrg[lane][0];
#pragma unroll
    for (int r = 0; r < 4; ++r) {
      float m1 = mb[16 + r];
      float mm = fmaxf(mrun[r], m1);
      float e0 = __expf(mrun[r] - mm), e1 = __expf(m1 - mm);
      float lc = lrun[r] * e0 + mb[20 + r] * e1;
      float inv = 1.f / lc;
#pragma unroll
      for (int fv = 0; fv < 4; ++fv) {
        float oc = o[fv][r] * e0 + mb[fv * 4 + r] * e1;
        attb[(size_t)(b * S + i0 + g * 4 + r) * 512 + h * 64 + fv * 16 + l16] =
            f2bf(oc * inv);
      }
    }
  }
}

extern "C" void kernel_launch(void* const* d_in, const int* in_sizes, int n_in,
                              void* d_out, int out_size, void* d_ws, size_t ws_size,
                              hipStream_t stream) {
  const float* x = (const float*)d_in[0];
  const float* W_qkv = (const float*)d_in[2];
  const float* b_qkv = (const float*)d_in[3];
  const float* W_proj = (const float*)d_in[4];
  const float* b_proj = (const float*)d_in[5];
  const float* E = (const float*)d_in[6];
  const float* g1 = (const float*)d_in[7];
  const float* be1 = (const float*)d_in[8];
  const float* g2 = (const float*)d_in[9];
  const float* be2 = (const float*)d_in[10];
  const float* W_fc1 = (const float*)d_in[11];
  const float* b_fc1 = (const float*)d_in[12];
  const float* W_fc2 = (const float*)d_in[13];
  const float* b_fc2 = (const float*)d_in[14];

  float* x_out = (float*)d_out;                 // 2*2048*512 f32
  float* present = x_out + 2097152;             // (2,2,8,2048,64) f32

  char* ws = (char*)d_ws;
  ushort* a_bf   = (ushort*)(ws + 0);           // 4096x512 bf16
  ushort* m_bf   = (ushort*)(ws + 4194304);     // 4096x512 bf16
  ushort* q_bf   = (ushort*)(ws + 8388608);     // [b][h][s][64] bf16
  ushort* att_bf = (ushort*)(ws + 12582912);    // 4096x512 bf16
  ushort* h_bf   = (ushort*)(ws + 16777216);    // 4096x2048 bf16 (fc1 out)
  ushort* k_bf   = (ushort*)(ws + 16777216);    // aliased: [b][h][s][64] bf16 (pre-fc1)
  ushort* vt_bf  = (ushort*)(ws + 20971520);    // aliased: [b][h][64][s] bf16 (pre-fc1)
  float*  x2     = (float*)(ws + 33554432);     // 4096x512 f32
  ushort* Wqkv_t = (ushort*)(ws + 41943040);    // 1536x512 bf16
  ushort* Wproj_t= (ushort*)(ws + 43515904);    // 512x512 bf16
  ushort* Wfc1_t = (ushort*)(ws + 44040192);    // 2048x512 bf16
  ushort* Wfc2_t = (ushort*)(ws + 46137344);    // 512x2048 bf16
  ushort* E_bf   = (ushort*)(ws + 48234496);    // 8x2048x64 bf16

  k_transpose_bf<<<dim3(48, 16), 256, 0, stream>>>(W_qkv, Wqkv_t, 512, 1536);
  k_transpose_bf<<<dim3(16, 16), 256, 0, stream>>>(W_proj, Wproj_t, 512, 512);
  k_transpose_bf<<<dim3(64, 16), 256, 0, stream>>>(W_fc1, Wfc1_t, 512, 2048);
  k_transpose_bf<<<dim3(16, 64), 256, 0, stream>>>(W_fc2, Wfc2_t, 2048, 512);
  k_cvt_bf<<<1024, 256, 0, stream>>>(E, E_bf, 262144);
  k_ln<<<1024, 256, 0, stream>>>(x, g1, be1, a_bf);
  k_gemm<0, 128><<<dim3(12, 32), 256, 0, stream>>>(a_bf, Wqkv_t, 4096, 1536, 512,
                                                   b_qkv, nullptr, nullptr, nullptr,
                                                   present, q_bf, k_bf, vt_bf);
  k_attn<<<2048, 128, 0, stream>>>(q_bf, k_bf, vt_bf, E_bf, att_bf);
  k_gemm<1, 64><<<dim3(8, 32), 256, 0, stream>>>(att_bf, Wproj_t, 4096, 512, 512,
                                                 b_proj, x, x2, nullptr, nullptr, nullptr,
                                                 nullptr, nullptr);
  k_ln<<<1024, 256, 0, stream>>>(x2, g2, be2, m_bf);
  k_gemm<2, 128><<<dim3(16, 32), 256, 0, stream>>>(m_bf, Wfc1_t, 4096, 2048, 512,
                                                   b_fc1, nullptr, nullptr, h_bf, nullptr,
                                                   nullptr, nullptr, nullptr);
  k_gemm<1, 64><<<dim3(8, 32), 256, 0, stream>>>(h_bf, Wfc2_t, 4096, 512, 2048,
                                                 b_fc2, x2, x_out, nullptr, nullptr, nullptr,
                                                 nullptr, nullptr);
}

// Round 8
// 290.094 us; speedup vs baseline: 1.1587x; 1.0758x over previous
//
#include <hip/hip_runtime.h>
#include <stdint.h>

#define DEV __device__ __forceinline__
#define SCHEDB __builtin_amdgcn_sched_barrier(0)
#define WAITVM(n) asm volatile("s_waitcnt vmcnt(" #n ")" ::: "memory")
#define WAITLG asm volatile("s_waitcnt lgkmcnt(0)" ::: "memory")

typedef __attribute__((ext_vector_type(8))) short bf16x8;
typedef __attribute__((ext_vector_type(4))) float f32x4;

DEV ushort f2bf(float f) {
  union { float f; uint32_t u; } c; c.f = f;
  return (ushort)((c.u + 0x7FFFu + ((c.u >> 16) & 1)) >> 16);
}
DEV bf16x8 ld8(const ushort* p) { return *reinterpret_cast<const bf16x8*>(p); }

DEV void gload16(const void* g, void* l) {
  __builtin_amdgcn_global_load_lds(
      (const __attribute__((address_space(1))) uint32_t*)g,
      (__attribute__((address_space(3))) uint32_t*)l, 16, 0, 0);
}

// ---------------- transpose f32 [R][C] -> bf16 [C][R] ----------------
__global__ __launch_bounds__(256) void k_transpose_bf(const float* __restrict__ in,
                                                      ushort* __restrict__ out,
                                                      int R, int C) {
  __shared__ float t[32][33];
  int tx = threadIdx.x & 31, ty = threadIdx.x >> 5;
  int c0 = blockIdx.x * 32, r0 = blockIdx.y * 32;
#pragma unroll
  for (int k = 0; k < 4; ++k)
    t[ty + 8 * k][tx] = in[(size_t)(r0 + ty + 8 * k) * C + c0 + tx];
  __syncthreads();
#pragma unroll
  for (int k = 0; k < 4; ++k)
    out[(size_t)(c0 + ty + 8 * k) * R + r0 + tx] = f2bf(t[tx][ty + 8 * k]);
}

// ---------------- elementwise f32 -> bf16 ----------------
__global__ __launch_bounds__(256) void k_cvt_bf(const float* __restrict__ in,
                                                ushort* __restrict__ out, int n4) {
  int i = blockIdx.x * 256 + threadIdx.x;
  if (i >= n4) return;
  float4 v = reinterpret_cast<const float4*>(in)[i];
  ushort4 o; o.x = f2bf(v.x); o.y = f2bf(v.y); o.z = f2bf(v.z); o.w = f2bf(v.w);
  reinterpret_cast<ushort4*>(out)[i] = o;
}

// ---------------- layernorm: f32 [4096][512] -> bf16 (4 rows/block) ----------------
__global__ __launch_bounds__(256) void k_ln(const float* __restrict__ x,
                                            const float* __restrict__ g,
                                            const float* __restrict__ be,
                                            ushort* __restrict__ out) {
  int w = threadIdx.x >> 6, lane = threadIdx.x & 63;
  int row = blockIdx.x * 4 + w;
  const float* xr = x + (size_t)row * 512 + lane * 8;
  float4 a = *reinterpret_cast<const float4*>(xr);
  float4 b = *reinterpret_cast<const float4*>(xr + 4);
  float xs[8] = {a.x, a.y, a.z, a.w, b.x, b.y, b.z, b.w};
  float s = 0.f, q = 0.f;
#pragma unroll
  for (int i = 0; i < 8; ++i) { s += xs[i]; q += xs[i] * xs[i]; }
#pragma unroll
  for (int off = 32; off; off >>= 1) { s += __shfl_xor(s, off); q += __shfl_xor(q, off); }
  float mu = s * (1.f / 512.f);
  float var = q * (1.f / 512.f) - mu * mu;
  float inv = rsqrtf(var + 1e-5f);
  const float* gp = g + lane * 8;
  const float* bp = be + lane * 8;
  ushort o[8];
#pragma unroll
  for (int i = 0; i < 8; ++i) o[i] = f2bf((xs[i] - mu) * inv * gp[i] + bp[i]);
  *reinterpret_cast<uint4*>(out + (size_t)row * 512 + lane * 8) = *reinterpret_cast<uint4*>(o);
}

// ---------------- GEMM: counted-vmcnt 2-phase double-buffered ----------------
template <int EPI, int BN>
__global__ __launch_bounds__(256) void k_gemm(
    const ushort* __restrict__ A, const ushort* __restrict__ Bt,
    int M, int N, int K,
    const float* __restrict__ bias, const float* __restrict__ res,
    float* __restrict__ outf, ushort* __restrict__ outb,
    float* __restrict__ present, ushort* __restrict__ qbf,
    ushort* __restrict__ kbf, ushort* __restrict__ vtbf) {
  constexpr int NF = BN / 32;
  __shared__ ushort As[2][128][64];
  __shared__ ushort Bs[2][BN][64];
  const int tid = threadIdx.x, lane = tid & 63, w = tid >> 6;
  const int g = lane >> 4, l16 = lane & 15;
  const int m0 = blockIdx.y * 128, n0 = blockIdx.x * BN;
  const int wm = (w >> 1) * 64, wn = (w & 1) * (BN / 2);
  f32x4 acc[4][NF];
#pragma unroll
  for (int i = 0; i < 4; ++i)
#pragma unroll
    for (int j = 0; j < NF; ++j) acc[i][j] = (f32x4){0.f, 0.f, 0.f, 0.f};

  const int lrow_off = (lane << 4);
  auto stage = [&](int buf, int k0) {
#pragma unroll
    for (int sw = 0; sw < 4; ++sw) {
      int offb = sw * 4096 + w * 1024;
      int loff = offb + lrow_off;
      int row = loff >> 7, colb = loff & 127;
      gload16((const char*)A + (((size_t)(m0 + row) * K + k0) << 1) + colb,
              (char*)(&As[buf][0][0]) + offb);
    }
#pragma unroll
    for (int sw = 0; sw < BN / 32; ++sw) {
      int offb = sw * 4096 + w * 1024;
      int loff = offb + lrow_off;
      int row = loff >> 7, colb = loff & 127;
      gload16((const char*)Bt + (((size_t)(n0 + row) * K + k0) << 1) + colb,
              (char*)(&Bs[buf][0][0]) + offb);
    }
  };

  const int nt = K >> 6;
  stage(0, 0);
  stage(1, 64);
  if constexpr (BN == 128) WAITVM(8); else WAITVM(6);
  SCHEDB;
  __builtin_amdgcn_s_barrier();
  SCHEDB;

  for (int t = 0; t < nt; ++t) {
    const int cur = t & 1;
    bf16x8 af[2][4], bfr[2][NF];
#pragma unroll
    for (int kk = 0; kk < 2; ++kk) {
#pragma unroll
      for (int f = 0; f < 4; ++f)
        af[kk][f] = *reinterpret_cast<const bf16x8*>(
            &As[cur][wm + f * 16 + l16][kk * 32 + g * 8]);
#pragma unroll
      for (int f = 0; f < NF; ++f)
        bfr[kk][f] = *reinterpret_cast<const bf16x8*>(
            &Bs[cur][wn + f * 16 + l16][kk * 32 + g * 8]);
    }
    WAITLG;
    SCHEDB;
    __builtin_amdgcn_s_barrier();
    SCHEDB;
    if (t + 2 < nt) stage(cur, (t + 2) << 6);
    SCHEDB;
#pragma unroll
    for (int kk = 0; kk < 2; ++kk)
#pragma unroll
      for (int i = 0; i < 4; ++i)
#pragma unroll
        for (int j = 0; j < NF; ++j)
          acc[i][j] = __builtin_amdgcn_mfma_f32_16x16x32_bf16(
              af[kk][i], bfr[kk][j], acc[i][j], 0, 0, 0);
    SCHEDB;
    if (t + 1 < nt) {
      if (t + 2 < nt) {
        if constexpr (BN == 128) WAITVM(8); else WAITVM(6);
      } else {
        WAITVM(0);
      }
      SCHEDB;
      __builtin_amdgcn_s_barrier();
      SCHEDB;
    }
  }

#pragma unroll
  for (int i = 0; i < 4; ++i)
#pragma unroll
    for (int j = 0; j < NF; ++j)
#pragma unroll
      for (int r = 0; r < 4; ++r) {
        int row = m0 + wm + i * 16 + g * 4 + r;
        int col = n0 + wn + j * 16 + l16;
        float v = acc[i][j][r] + bias[col];
        if constexpr (EPI == 0) {
          int third = col >> 9, hh = (col >> 6) & 7, d = col & 63;
          int bb = row >> 11, sq = row & 2047;
          if (third == 0) {
            qbf[((((size_t)bb * 8 + hh) * 2048) + sq) * 64 + d] = f2bf(v);
          } else {
            present[((((size_t)bb * 2 + (third - 1)) * 8 + hh) * 2048 + sq) * 64 + d] = v;
            if (third == 1)
              kbf[((((size_t)bb * 8 + hh) * 2048) + sq) * 64 + d] = f2bf(v);
            else
              vtbf[(((size_t)bb * 8 + hh) * 64 + d) * 2048 + sq] = f2bf(v);
          }
        } else if constexpr (EPI == 1) {
          size_t idx = (size_t)row * N + col;
          outf[idx] = v + res[idx];
        } else {
          float u = 0.7978845608f * (v + 0.044715f * v * v * v);
          float e = __expf(2.f * u);
          float th = 1.f - 2.f / (e + 1.f);
          outb[(size_t)row * N + col] = f2bf(0.5f * v * (1.f + th));
        }
      }
}

// ---------------- fused causal attention, LDS-staged 64-row blocks ----------------
// 512 blocks x 256 threads (4 waves). Block = (bh, 64 q-rows); wave = 16-row strip.
// K/V^T/E-band staged per k-tile via global_load_lds (pre-inverse-swizzled global
// source, XOR-swizzled ds_read), double-buffered, shared by all 4 waves.
__global__ __launch_bounds__(256, 2) void k_attn(
    const ushort* __restrict__ qbf, const ushort* __restrict__ kbf,
    const ushort* __restrict__ vtbf, const ushort* __restrict__ Ebf,
    ushort* __restrict__ attb) {
  constexpr int S = 2048;
  __shared__ ushort Ks[2][64][64];
  __shared__ ushort Vs[2][64][64];
  __shared__ ushort Es[2][128][64];
  __shared__ ushort Ps[4][16][76];
  const int tid = threadIdx.x, lane = tid & 63, w = tid >> 6;
  const int g = lane >> 4, l16 = lane & 15;
  const int bid = blockIdx.x;
  const int h = bid & 7, rest = bid >> 3;
  const int b = rest & 1, tq = 31 - (rest >> 1);  // heavy first
  const int bh = b * 8 + h;

  const ushort* qp = qbf + (size_t)bh * S * 64;
  const ushort* kp = kbf + (size_t)bh * S * 64;
  const ushort* vp = vtbf + (size_t)bh * 64 * S;
  const ushort* ep = Ebf + (size_t)h * S * 64;

  const int i0 = tq * 64;
  const int iw = i0 + w * 16;         // this wave's 16-row strip
  const int rbase = 48 - w * 16;      // strip's E-window offset in staged band

  bf16x8 qf[2];
  qf[0] = ld8(qp + (size_t)(iw + l16) * 64 + g * 8);
  qf[1] = ld8(qp + (size_t)(iw + l16) * 64 + 32 + g * 8);
  f32x4 o[4];
#pragma unroll
  for (int fv = 0; fv < 4; ++fv) o[fv] = (f32x4){0.f, 0.f, 0.f, 0.f};
  float mrun[4], lrun[4];
#pragma unroll
  for (int r = 0; r < 4; ++r) { mrun[r] = -1e30f; lrun[r] = 0.f; }
  const int nkt = tq + 1;

  // stage k-tile kt into buffer buf. LDS dest is wave-uniform (HW adds lane*16);
  // global source is per-lane pre-inverse-swizzled so swizzled ds_reads are
  // conflict-free (rule: linear dest + inv-swz source + swz read).
  auto stage = [&](int buf, int kt) {
    const int j0 = kt * 64;
    const int ebase = S - 64 - i0 + j0;
#pragma unroll
    for (int c = 0; c < 2; ++c) {
      int chunk = w * 2 + c;                 // 1KB chunk id (8 rows)
      int row = chunk * 8 + (lane >> 3);
      int ccp = (lane & 7) ^ (row & 7);
      gload16(kp + (size_t)(j0 + row) * 64 + ccp * 8,
              (char*)(&Ks[buf][0][0]) + chunk * 1024);
      gload16(vp + (size_t)row * S + j0 + ccp * 8,
              (char*)(&Vs[buf][0][0]) + chunk * 1024);
    }
#pragma unroll
    for (int c = 0; c < 4; ++c) {
      int chunk = w * 4 + c;
      int row = chunk * 8 + (lane >> 3);
      int l = ebase + row;
      l = l < 0 ? 0 : (l > S - 1 ? S - 1 : l);
      int ccp = (lane & 7) ^ (row & 7);
      gload16(ep + (size_t)l * 64 + ccp * 8,
              (char*)(&Es[buf][0][0]) + chunk * 1024);
    }
  };

  stage(0, 0);
  WAITVM(0);
  SCHEDB;
  __builtin_amdgcn_s_barrier();
  SCHEDB;

  for (int kt = 0; kt < nkt; ++kt) {
    const int cur = kt & 1;
    const int j0 = kt * 64;
    if (kt + 1 < nkt) stage(cur ^ 1, kt + 1);  // async prefetch into other buffer
    SCHEDB;
    const char* KsB = (const char*)&Ks[cur][0][0];
    const char* VsB = (const char*)&Vs[cur][0][0];
    const char* EsB = (const char*)&Es[cur][0][0];

    // ---- QK^T from swizzled LDS ----
    f32x4 sacc[4];
#pragma unroll
    for (int fn = 0; fn < 4; ++fn) sacc[fn] = (f32x4){0.f, 0.f, 0.f, 0.f};
#pragma unroll
    for (int kk = 0; kk < 2; ++kk)
#pragma unroll
      for (int fn = 0; fn < 4; ++fn) {
        int row = fn * 16 + l16, chunk = kk * 4 + g;
        bf16x8 kfr = ld8((const ushort*)(KsB + row * 128 + (((chunk ^ (row & 7))) << 4)));
        sacc[fn] = __builtin_amdgcn_mfma_f32_16x16x32_bf16(qf[kk], kfr, sacc[fn], 0, 0, 0);
      }
    // ---- relative band ----
    f32x4 racc[5];
#pragma unroll
    for (int fc = 0; fc < 5; ++fc) racc[fc] = (f32x4){0.f, 0.f, 0.f, 0.f};
#pragma unroll
    for (int kk = 0; kk < 2; ++kk)
#pragma unroll
      for (int fc = 0; fc < 5; ++fc) {
        int row = rbase + fc * 16 + l16, chunk = kk * 4 + g;
        bf16x8 efr = ld8((const ushort*)(EsB + row * 128 + (((chunk ^ (row & 7))) << 4)));
        racc[fc] = __builtin_amdgcn_mfma_f32_16x16x32_bf16(qf[kk], efr, racc[fc], 0, 0, 0);
      }

    // ---- skew gather via in-wave shuffle + mask + online softmax ----
    float Sv[4][4], mtile[4];
#pragma unroll
    for (int r = 0; r < 4; ++r) mtile[r] = -1e30f;
#pragma unroll
    for (int r = 0; r < 4; ++r) {
      const int dr = g * 4 + r;
      const int src = (lane & 48) | ((l16 + 15 - dr) & 15);
      const bool hi = (l16 > dr);
#pragma unroll
      for (int fn = 0; fn < 4; ++fn) {
        float lo_v = __shfl(racc[fn][r], src);
        float hi_v = __shfl(racc[fn + 1][r], src);
        float rel = hi ? hi_v : lo_v;
        float sv = (sacc[fn][r] + rel) * 0.125f;
        int dj = fn * 16 + l16;
        if (j0 + dj > iw + dr) sv = -1e30f;
        Sv[fn][r] = sv;
        mtile[r] = fmaxf(mtile[r], sv);
      }
    }
#pragma unroll
    for (int off = 1; off < 16; off <<= 1)
#pragma unroll
      for (int r = 0; r < 4; ++r) mtile[r] = fmaxf(mtile[r], __shfl_xor(mtile[r], off));
    float corr[4], psum[4];
#pragma unroll
    for (int r = 0; r < 4; ++r) {
      float mn = fmaxf(mrun[r], mtile[r]);
      corr[r] = __expf(mrun[r] - mn);
      mrun[r] = mn;
      psum[r] = 0.f;
    }
#pragma unroll
    for (int fn = 0; fn < 4; ++fn)
#pragma unroll
      for (int r = 0; r < 4; ++r) {
        float pv = __expf(Sv[fn][r] - mrun[r]);
        psum[r] += pv;
        Ps[w][g * 4 + r][fn * 16 + l16] = f2bf(pv);
      }
#pragma unroll
    for (int off = 1; off < 16; off <<= 1)
#pragma unroll
      for (int r = 0; r < 4; ++r) psum[r] += __shfl_xor(psum[r], off);
#pragma unroll
    for (int r = 0; r < 4; ++r) lrun[r] = lrun[r] * corr[r] + psum[r];
#pragma unroll
    for (int fv = 0; fv < 4; ++fv)
#pragma unroll
      for (int r = 0; r < 4; ++r) o[fv][r] *= corr[r];

    // ---- PV from swizzled LDS ----
#pragma unroll
    for (int kk = 0; kk < 2; ++kk) {
      bf16x8 pf = ld8(&Ps[w][l16][kk * 32 + g * 8]);
#pragma unroll
      for (int fv = 0; fv < 4; ++fv) {
        int row = fv * 16 + l16, chunk = kk * 4 + g;
        bf16x8 vfr = ld8((const ushort*)(VsB + row * 128 + (((chunk ^ (row & 7))) << 4)));
        o[fv] = __builtin_amdgcn_mfma_f32_16x16x32_bf16(pf, vfr, o[fv], 0, 0, 0);
      }
    }
    SCHEDB;
    if (kt + 1 < nkt) {
      WAITVM(0);  // next tile staged
      SCHEDB;
      __builtin_amdgcn_s_barrier();  // all waves done with cur + next ready
      SCHEDB;
    }
  }

  // ---- epilogue: no k-split, direct store ----
#pragma unroll
  for (int fv = 0; fv < 4; ++fv)
#pragma unroll
    for (int r = 0; r < 4; ++r) {
      int dr = g * 4 + r;
      float v = o[fv][r] / lrun[r];
      attb[(size_t)(b * S + iw + dr) * 512 + h * 64 + fv * 16 + l16] = f2bf(v);
    }
}

extern "C" void kernel_launch(void* const* d_in, const int* in_sizes, int n_in,
                              void* d_out, int out_size, void* d_ws, size_t ws_size,
                              hipStream_t stream) {
  const float* x = (const float*)d_in[0];
  const float* W_qkv = (const float*)d_in[2];
  const float* b_qkv = (const float*)d_in[3];
  const float* W_proj = (const float*)d_in[4];
  const float* b_proj = (const float*)d_in[5];
  const float* E = (const float*)d_in[6];
  const float* g1 = (const float*)d_in[7];
  const float* be1 = (const float*)d_in[8];
  const float* g2 = (const float*)d_in[9];
  const float* be2 = (const float*)d_in[10];
  const float* W_fc1 = (const float*)d_in[11];
  const float* b_fc1 = (const float*)d_in[12];
  const float* W_fc2 = (const float*)d_in[13];
  const float* b_fc2 = (const float*)d_in[14];

  float* x_out = (float*)d_out;                 // 2*2048*512 f32
  float* present = x_out + 2097152;             // (2,2,8,2048,64) f32

  char* ws = (char*)d_ws;
  ushort* a_bf   = (ushort*)(ws + 0);           // 4096x512 bf16
  ushort* m_bf   = (ushort*)(ws + 4194304);     // 4096x512 bf16
  ushort* q_bf   = (ushort*)(ws + 8388608);     // [b][h][s][64] bf16
  ushort* att_bf = (ushort*)(ws + 12582912);    // 4096x512 bf16
  ushort* h_bf   = (ushort*)(ws + 16777216);    // 4096x2048 bf16 (fc1 out)
  ushort* k_bf   = (ushort*)(ws + 16777216);    // aliased: [b][h][s][64] bf16 (pre-fc1)
  ushort* vt_bf  = (ushort*)(ws + 20971520);    // aliased: [b][h][64][s] bf16 (pre-fc1)
  float*  x2     = (float*)(ws + 33554432);     // 4096x512 f32
  ushort* Wqkv_t = (ushort*)(ws + 41943040);    // 1536x512 bf16
  ushort* Wproj_t= (ushort*)(ws + 43515904);    // 512x512 bf16
  ushort* Wfc1_t = (ushort*)(ws + 44040192);    // 2048x512 bf16
  ushort* Wfc2_t = (ushort*)(ws + 46137344);    // 512x2048 bf16
  ushort* E_bf   = (ushort*)(ws + 48234496);    // 8x2048x64 bf16

  k_transpose_bf<<<dim3(48, 16), 256, 0, stream>>>(W_qkv, Wqkv_t, 512, 1536);
  k_transpose_bf<<<dim3(16, 16), 256, 0, stream>>>(W_proj, Wproj_t, 512, 512);
  k_transpose_bf<<<dim3(64, 16), 256, 0, stream>>>(W_fc1, Wfc1_t, 512, 2048);
  k_transpose_bf<<<dim3(16, 64), 256, 0, stream>>>(W_fc2, Wfc2_t, 2048, 512);
  k_cvt_bf<<<1024, 256, 0, stream>>>(E, E_bf, 262144);
  k_ln<<<1024, 256, 0, stream>>>(x, g1, be1, a_bf);
  k_gemm<0, 128><<<dim3(12, 32), 256, 0, stream>>>(a_bf, Wqkv_t, 4096, 1536, 512,
                                                   b_qkv, nullptr, nullptr, nullptr,
                                                   present, q_bf, k_bf, vt_bf);
  k_attn<<<512, 256, 0, stream>>>(q_bf, k_bf, vt_bf, E_bf, att_bf);
  k_gemm<1, 64><<<dim3(8, 32), 256, 0, stream>>>(att_bf, Wproj_t, 4096, 512, 512,
                                                 b_proj, x, x2, nullptr, nullptr, nullptr,
                                                 nullptr, nullptr);
  k_ln<<<1024, 256, 0, stream>>>(x2, g2, be2, m_bf);
  k_gemm<2, 128><<<dim3(16, 32), 256, 0, stream>>>(m_bf, Wfc1_t, 4096, 2048, 512,
                                                   b_fc1, nullptr, nullptr, h_bf, nullptr,
                                                   nullptr, nullptr, nullptr);
  k_gemm<1, 64><<<dim3(8, 32), 256, 0, stream>>>(h_bf, Wfc2_t, 4096, 512, 2048,
                                                 b_fc2, x2, x_out, nullptr, nullptr, nullptr,
                                                 nullptr, nullptr);
}

// Round 10
// 273.230 us; speedup vs baseline: 1.2302x; 1.0617x over previous
//
#include <hip/hip_runtime.h>
#include <stdint.h>

#define DEV __device__ __forceinline__
#define SCHEDB __builtin_amdgcn_sched_barrier(0)
#define WAITVM(n) asm volatile("s_waitcnt vmcnt(" #n ")" ::: "memory")
#define WAITLG asm volatile("s_waitcnt lgkmcnt(0)" ::: "memory")

typedef __attribute__((ext_vector_type(8))) short bf16x8;
typedef __attribute__((ext_vector_type(4))) float f32x4;

DEV ushort f2bf(float f) {
  union { float f; uint32_t u; } c; c.f = f;
  return (ushort)((c.u + 0x7FFFu + ((c.u >> 16) & 1)) >> 16);
}
DEV bf16x8 ld8(const ushort* p) { return *reinterpret_cast<const bf16x8*>(p); }

DEV void gload16(const void* g, void* l) {
  __builtin_amdgcn_global_load_lds(
      (const __attribute__((address_space(1))) uint32_t*)g,
      (__attribute__((address_space(3))) uint32_t*)l, 16, 0, 0);
}

// ---------------- transpose f32 [R][C] -> bf16 [C][R] ----------------
__global__ __launch_bounds__(256) void k_transpose_bf(const float* __restrict__ in,
                                                      ushort* __restrict__ out,
                                                      int R, int C) {
  __shared__ float t[32][33];
  int tx = threadIdx.x & 31, ty = threadIdx.x >> 5;
  int c0 = blockIdx.x * 32, r0 = blockIdx.y * 32;
#pragma unroll
  for (int k = 0; k < 4; ++k)
    t[ty + 8 * k][tx] = in[(size_t)(r0 + ty + 8 * k) * C + c0 + tx];
  __syncthreads();
#pragma unroll
  for (int k = 0; k < 4; ++k)
    out[(size_t)(c0 + ty + 8 * k) * R + r0 + tx] = f2bf(t[tx][ty + 8 * k]);
}

// ---------------- elementwise f32 -> bf16 ----------------
__global__ __launch_bounds__(256) void k_cvt_bf(const float* __restrict__ in,
                                                ushort* __restrict__ out, int n4) {
  int i = blockIdx.x * 256 + threadIdx.x;
  if (i >= n4) return;
  float4 v = reinterpret_cast<const float4*>(in)[i];
  ushort4 o; o.x = f2bf(v.x); o.y = f2bf(v.y); o.z = f2bf(v.z); o.w = f2bf(v.w);
  reinterpret_cast<ushort4*>(out)[i] = o;
}

// ---------------- layernorm: f32 [4096][512] -> bf16 (4 rows/block) ----------------
__global__ __launch_bounds__(256) void k_ln(const float* __restrict__ x,
                                            const float* __restrict__ g,
                                            const float* __restrict__ be,
                                            ushort* __restrict__ out) {
  int w = threadIdx.x >> 6, lane = threadIdx.x & 63;
  int row = blockIdx.x * 4 + w;
  const float* xr = x + (size_t)row * 512 + lane * 8;
  float4 a = *reinterpret_cast<const float4*>(xr);
  float4 b = *reinterpret_cast<const float4*>(xr + 4);
  float xs[8] = {a.x, a.y, a.z, a.w, b.x, b.y, b.z, b.w};
  float s = 0.f, q = 0.f;
#pragma unroll
  for (int i = 0; i < 8; ++i) { s += xs[i]; q += xs[i] * xs[i]; }
#pragma unroll
  for (int off = 32; off; off >>= 1) { s += __shfl_xor(s, off); q += __shfl_xor(q, off); }
  float mu = s * (1.f / 512.f);
  float var = q * (1.f / 512.f) - mu * mu;
  float inv = rsqrtf(var + 1e-5f);
  const float* gp = g + lane * 8;
  const float* bp = be + lane * 8;
  ushort o[8];
#pragma unroll
  for (int i = 0; i < 8; ++i) o[i] = f2bf((xs[i] - mu) * inv * gp[i] + bp[i]);
  *reinterpret_cast<uint4*>(out + (size_t)row * 512 + lane * 8) = *reinterpret_cast<uint4*>(o);
}

// ---------------- GEMM: counted-vmcnt 2-phase, XOR-swizzled LDS ----------------
// LDS rows are 128B; without swizzle the fragment read (16 lanes, stride 1 row)
// is a 16-way bank conflict. Swizzle: linear LDS dest + inverse-swizzled global
// source chunk + swizzled read (rule #21).
template <int EPI, int BN>
__global__ __launch_bounds__(256) void k_gemm(
    const ushort* __restrict__ A, const ushort* __restrict__ Bt,
    int M, int N, int K,
    const float* __restrict__ bias, const float* __restrict__ res,
    float* __restrict__ outf, ushort* __restrict__ outb,
    float* __restrict__ present, ushort* __restrict__ qbf,
    ushort* __restrict__ kbf, ushort* __restrict__ vtbf) {
  constexpr int NF = BN / 32;
  __shared__ ushort As[2][128][64];
  __shared__ ushort Bs[2][BN][64];
  const int tid = threadIdx.x, lane = tid & 63, w = tid >> 6;
  const int g = lane >> 4, l16 = lane & 15;
  const int m0 = blockIdx.y * 128, n0 = blockIdx.x * BN;
  const int wm = (w >> 1) * 64, wn = (w & 1) * (BN / 2);
  f32x4 acc[4][NF];
#pragma unroll
  for (int i = 0; i < 4; ++i)
#pragma unroll
    for (int j = 0; j < NF; ++j) acc[i][j] = (f32x4){0.f, 0.f, 0.f, 0.f};

  // stage: 1KB chunk = 8 rows x 8 slots of 16B. lane -> row chunk*8+(lane>>3),
  // slot lane&7. Source fetches global col-chunk (lane&7)^(row&7).
  auto stage = [&](int buf, int k0) {
#pragma unroll
    for (int sw = 0; sw < 4; ++sw) {
      int chunk = sw * 4 + w;
      int row = chunk * 8 + (lane >> 3);
      int ccp = (lane & 7) ^ (row & 7);
      gload16((const char*)A + (((size_t)(m0 + row) * K + k0) << 1) + (ccp << 4),
              (char*)(&As[buf][0][0]) + chunk * 1024);
    }
#pragma unroll
    for (int sw = 0; sw < BN / 32; ++sw) {
      int chunk = sw * 4 + w;
      int row = chunk * 8 + (lane >> 3);
      int ccp = (lane & 7) ^ (row & 7);
      gload16((const char*)Bt + (((size_t)(n0 + row) * K + k0) << 1) + (ccp << 4),
              (char*)(&Bs[buf][0][0]) + chunk * 1024);
    }
  };

  const int nt = K >> 6;
  stage(0, 0);
  stage(1, 64);
  if constexpr (BN == 128) WAITVM(8); else WAITVM(6);
  SCHEDB;
  __builtin_amdgcn_s_barrier();
  SCHEDB;

  const char* AsB0 = (const char*)&As[0][0][0];
  const char* BsB0 = (const char*)&Bs[0][0][0];
  for (int t = 0; t < nt; ++t) {
    const int cur = t & 1;
    const char* AsB = AsB0 + cur * (128 * 128);
    const char* BsB = BsB0 + cur * (BN * 128);
    bf16x8 af[2][4], bfr[2][NF];
#pragma unroll
    for (int kk = 0; kk < 2; ++kk) {
#pragma unroll
      for (int f = 0; f < 4; ++f) {
        int row = wm + f * 16 + l16;
        af[kk][f] = ld8((const ushort*)(AsB + row * 128 + (((kk * 4 + g) ^ (row & 7)) << 4)));
      }
#pragma unroll
      for (int f = 0; f < NF; ++f) {
        int row = wn + f * 16 + l16;
        bfr[kk][f] = ld8((const ushort*)(BsB + row * 128 + (((kk * 4 + g) ^ (row & 7)) << 4)));
      }
    }
    WAITLG;
    SCHEDB;
    __builtin_amdgcn_s_barrier();
    SCHEDB;
    if (t + 2 < nt) stage(cur, (t + 2) << 6);
    SCHEDB;
#pragma unroll
    for (int kk = 0; kk < 2; ++kk)
#pragma unroll
      for (int i = 0; i < 4; ++i)
#pragma unroll
        for (int j = 0; j < NF; ++j)
          acc[i][j] = __builtin_amdgcn_mfma_f32_16x16x32_bf16(
              af[kk][i], bfr[kk][j], acc[i][j], 0, 0, 0);
    SCHEDB;
    if (t + 1 < nt) {
      if (t + 2 < nt) {
        if constexpr (BN == 128) WAITVM(8); else WAITVM(6);
      } else {
        WAITVM(0);
      }
      SCHEDB;
      __builtin_amdgcn_s_barrier();
      SCHEDB;
    }
  }

#pragma unroll
  for (int i = 0; i < 4; ++i)
#pragma unroll
    for (int j = 0; j < NF; ++j)
#pragma unroll
      for (int r = 0; r < 4; ++r) {
        int row = m0 + wm + i * 16 + g * 4 + r;
        int col = n0 + wn + j * 16 + l16;
        float v = acc[i][j][r] + bias[col];
        if constexpr (EPI == 0) {
          int third = col >> 9, hh = (col >> 6) & 7, d = col & 63;
          int bb = row >> 11, sq = row & 2047;
          if (third == 0) {
            qbf[((((size_t)bb * 8 + hh) * 2048) + sq) * 64 + d] = f2bf(v);
          } else {
            present[((((size_t)bb * 2 + (third - 1)) * 8 + hh) * 2048 + sq) * 64 + d] = v;
            if (third == 1)
              kbf[((((size_t)bb * 8 + hh) * 2048) + sq) * 64 + d] = f2bf(v);
            else
              vtbf[(((size_t)bb * 8 + hh) * 64 + d) * 2048 + sq] = f2bf(v);
          }
        } else if constexpr (EPI == 1) {
          size_t idx = (size_t)row * N + col;
          outf[idx] = v + res[idx];
        } else {
          float u = 0.7978845608f * (v + 0.044715f * v * v * v);
          float e = __expf(2.f * u);
          float th = 1.f - 2.f / (e + 1.f);
          outb[(size_t)row * N + col] = f2bf(0.5f * v * (1.f + th));
        }
      }
}

// ---------------- fused causal attention, LDS-staged 64-row blocks ----------------
// 512 blocks x 256 threads (4 waves). Block = (bh, 64 q-rows); wave = 16-row strip.
// Complementary pairing: bids 0..255 take tq 31..16, bids 256..511 take tq 0..15
// so each CU's two blocks sum to ~34 tiles (was 49..19).
__global__ __launch_bounds__(256, 2) void k_attn(
    const ushort* __restrict__ qbf, const ushort* __restrict__ kbf,
    const ushort* __restrict__ vtbf, const ushort* __restrict__ Ebf,
    ushort* __restrict__ attb) {
  constexpr int S = 2048;
  __shared__ ushort Ks[2][64][64];
  __shared__ ushort Vs[2][64][64];
  __shared__ ushort Es[2][128][64];
  __shared__ ushort Ps[4][16][76];
  const int tid = threadIdx.x, lane = tid & 63, w = tid >> 6;
  const int g = lane >> 4, l16 = lane & 15;
  const int bid = blockIdx.x;
  const int h = bid & 7, rest = bid >> 3;
  const int b = rest & 1;
  const int tq = (rest < 32) ? (31 - (rest >> 1)) : ((rest - 32) >> 1);
  const int bh = b * 8 + h;

  const ushort* qp = qbf + (size_t)bh * S * 64;
  const ushort* kp = kbf + (size_t)bh * S * 64;
  const ushort* vp = vtbf + (size_t)bh * 64 * S;
  const ushort* ep = Ebf + (size_t)h * S * 64;

  const int i0 = tq * 64;
  const int iw = i0 + w * 16;
  const int rbase = 48 - w * 16;

  bf16x8 qf[2];
  qf[0] = ld8(qp + (size_t)(iw + l16) * 64 + g * 8);
  qf[1] = ld8(qp + (size_t)(iw + l16) * 64 + 32 + g * 8);
  f32x4 o[4];
#pragma unroll
  for (int fv = 0; fv < 4; ++fv) o[fv] = (f32x4){0.f, 0.f, 0.f, 0.f};
  float mrun[4], lrun[4];
#pragma unroll
  for (int r = 0; r < 4; ++r) { mrun[r] = -1e30f; lrun[r] = 0.f; }
  const int nkt = tq + 1;

  auto stage = [&](int buf, int kt) {
    const int j0 = kt * 64;
    const int ebase = S - 64 - i0 + j0;
#pragma unroll
    for (int c = 0; c < 2; ++c) {
      int chunk = w * 2 + c;
      int row = chunk * 8 + (lane >> 3);
      int ccp = (lane & 7) ^ (row & 7);
      gload16(kp + (size_t)(j0 + row) * 64 + ccp * 8,
              (char*)(&Ks[buf][0][0]) + chunk * 1024);
      gload16(vp + (size_t)row * S + j0 + ccp * 8,
              (char*)(&Vs[buf][0][0]) + chunk * 1024);
    }
#pragma unroll
    for (int c = 0; c < 4; ++c) {
      int chunk = w * 4 + c;
      int row = chunk * 8 + (lane >> 3);
      int l = ebase + row;
      l = l < 0 ? 0 : (l > S - 1 ? S - 1 : l);
      int ccp = (lane & 7) ^ (row & 7);
      gload16(ep + (size_t)l * 64 + ccp * 8,
              (char*)(&Es[buf][0][0]) + chunk * 1024);
    }
  };

  stage(0, 0);
  WAITVM(0);
  SCHEDB;
  __builtin_amdgcn_s_barrier();
  SCHEDB;

  for (int kt = 0; kt < nkt; ++kt) {
    const int cur = kt & 1;
    const int j0 = kt * 64;
    if (kt + 1 < nkt) stage(cur ^ 1, kt + 1);
    SCHEDB;
    const char* KsB = (const char*)&Ks[cur][0][0];
    const char* VsB = (const char*)&Vs[cur][0][0];
    const char* EsB = (const char*)&Es[cur][0][0];

    f32x4 sacc[4];
#pragma unroll
    for (int fn = 0; fn < 4; ++fn) sacc[fn] = (f32x4){0.f, 0.f, 0.f, 0.f};
#pragma unroll
    for (int kk = 0; kk < 2; ++kk)
#pragma unroll
      for (int fn = 0; fn < 4; ++fn) {
        int row = fn * 16 + l16, chunk = kk * 4 + g;
        bf16x8 kfr = ld8((const ushort*)(KsB + row * 128 + (((chunk ^ (row & 7))) << 4)));
        sacc[fn] = __builtin_amdgcn_mfma_f32_16x16x32_bf16(qf[kk], kfr, sacc[fn], 0, 0, 0);
      }
    f32x4 racc[5];
#pragma unroll
    for (int fc = 0; fc < 5; ++fc) racc[fc] = (f32x4){0.f, 0.f, 0.f, 0.f};
#pragma unroll
    for (int kk = 0; kk < 2; ++kk)
#pragma unroll
      for (int fc = 0; fc < 5; ++fc) {
        int row = rbase + fc * 16 + l16, chunk = kk * 4 + g;
        bf16x8 efr = ld8((const ushort*)(EsB + row * 128 + (((chunk ^ (row & 7))) << 4)));
        racc[fc] = __builtin_amdgcn_mfma_f32_16x16x32_bf16(qf[kk], efr, racc[fc], 0, 0, 0);
      }

    float Sv[4][4], mtile[4];
#pragma unroll
    for (int r = 0; r < 4; ++r) mtile[r] = -1e30f;
#pragma unroll
    for (int r = 0; r < 4; ++r) {
      const int dr = g * 4 + r;
      const int src = (lane & 48) | ((l16 + 15 - dr) & 15);
      const bool hi = (l16 > dr);
#pragma unroll
      for (int fn = 0; fn < 4; ++fn) {
        float lo_v = __shfl(racc[fn][r], src);
        float hi_v = __shfl(racc[fn + 1][r], src);
        float rel = hi ? hi_v : lo_v;
        float sv = (sacc[fn][r] + rel) * 0.125f;
        int dj = fn * 16 + l16;
        if (j0 + dj > iw + dr) sv = -1e30f;
        Sv[fn][r] = sv;
        mtile[r] = fmaxf(mtile[r], sv);
      }
    }
#pragma unroll
    for (int off = 1; off < 16; off <<= 1)
#pragma unroll
      for (int r = 0; r < 4; ++r) mtile[r] = fmaxf(mtile[r], __shfl_xor(mtile[r], off));
    float corr[4], psum[4];
#pragma unroll
    for (int r = 0; r < 4; ++r) {
      float mn = fmaxf(mrun[r], mtile[r]);
      corr[r] = __expf(mrun[r] - mn);
      mrun[r] = mn;
      psum[r] = 0.f;
    }
#pragma unroll
    for (int fn = 0; fn < 4; ++fn)
#pragma unroll
      for (int r = 0; r < 4; ++r) {
        float pv = __expf(Sv[fn][r] - mrun[r]);
        psum[r] += pv;
        Ps[w][g * 4 + r][fn * 16 + l16] = f2bf(pv);
      }
#pragma unroll
    for (int off = 1; off < 16; off <<= 1)
#pragma unroll
      for (int r = 0; r < 4; ++r) psum[r] += __shfl_xor(psum[r], off);
#pragma unroll
    for (int r = 0; r < 4; ++r) lrun[r] = lrun[r] * corr[r] + psum[r];
#pragma unroll
    for (int fv = 0; fv < 4; ++fv)
#pragma unroll
      for (int r = 0; r < 4; ++r) o[fv][r] *= corr[r];

#pragma unroll
    for (int kk = 0; kk < 2; ++kk) {
      bf16x8 pf = ld8(&Ps[w][l16][kk * 32 + g * 8]);
#pragma unroll
      for (int fv = 0; fv < 4; ++fv) {
        int row = fv * 16 + l16, chunk = kk * 4 + g;
        bf16x8 vfr = ld8((const ushort*)(VsB + row * 128 + (((chunk ^ (row & 7))) << 4)));
        o[fv] = __builtin_amdgcn_mfma_f32_16x16x32_bf16(pf, vfr, o[fv], 0, 0, 0);
      }
    }
    SCHEDB;
    if (kt + 1 < nkt) {
      WAITVM(0);
      SCHEDB;
      __builtin_amdgcn_s_barrier();
      SCHEDB;
    }
  }

#pragma unroll
  for (int fv = 0; fv < 4; ++fv)
#pragma unroll
    for (int r = 0; r < 4; ++r) {
      int dr = g * 4 + r;
      float v = o[fv][r] / lrun[r];
      attb[(size_t)(b * S + iw + dr) * 512 + h * 64 + fv * 16 + l16] = f2bf(v);
    }
}

extern "C" void kernel_launch(void* const* d_in, const int* in_sizes, int n_in,
                              void* d_out, int out_size, void* d_ws, size_t ws_size,
                              hipStream_t stream) {
  const float* x = (const float*)d_in[0];
  const float* W_qkv = (const float*)d_in[2];
  const float* b_qkv = (const float*)d_in[3];
  const float* W_proj = (const float*)d_in[4];
  const float* b_proj = (const float*)d_in[5];
  const float* E = (const float*)d_in[6];
  const float* g1 = (const float*)d_in[7];
  const float* be1 = (const float*)d_in[8];
  const float* g2 = (const float*)d_in[9];
  const float* be2 = (const float*)d_in[10];
  const float* W_fc1 = (const float*)d_in[11];
  const float* b_fc1 = (const float*)d_in[12];
  const float* W_fc2 = (const float*)d_in[13];
  const float* b_fc2 = (const float*)d_in[14];

  float* x_out = (float*)d_out;                 // 2*2048*512 f32
  float* present = x_out + 2097152;             // (2,2,8,2048,64) f32

  char* ws = (char*)d_ws;
  ushort* a_bf   = (ushort*)(ws + 0);           // 4096x512 bf16
  ushort* m_bf   = (ushort*)(ws + 4194304);     // 4096x512 bf16
  ushort* q_bf   = (ushort*)(ws + 8388608);     // [b][h][s][64] bf16
  ushort* att_bf = (ushort*)(ws + 12582912);    // 4096x512 bf16
  ushort* h_bf   = (ushort*)(ws + 16777216);    // 4096x2048 bf16 (fc1 out)
  ushort* k_bf   = (ushort*)(ws + 16777216);    // aliased: [b][h][s][64] bf16 (pre-fc1)
  ushort* vt_bf  = (ushort*)(ws + 20971520);    // aliased: [b][h][64][s] bf16 (pre-fc1)
  float*  x2     = (float*)(ws + 33554432);     // 4096x512 f32
  ushort* Wqkv_t = (ushort*)(ws + 41943040);    // 1536x512 bf16
  ushort* Wproj_t= (ushort*)(ws + 43515904);    // 512x512 bf16
  ushort* Wfc1_t = (ushort*)(ws + 44040192);    // 2048x512 bf16
  ushort* Wfc2_t = (ushort*)(ws + 46137344);    // 512x2048 bf16
  ushort* E_bf   = (ushort*)(ws + 48234496);    // 8x2048x64 bf16

  k_transpose_bf<<<dim3(48, 16), 256, 0, stream>>>(W_qkv, Wqkv_t, 512, 1536);
  k_transpose_bf<<<dim3(16, 16), 256, 0, stream>>>(W_proj, Wproj_t, 512, 512);
  k_transpose_bf<<<dim3(64, 16), 256, 0, stream>>>(W_fc1, Wfc1_t, 512, 2048);
  k_transpose_bf<<<dim3(16, 64), 256, 0, stream>>>(W_fc2, Wfc2_t, 2048, 512);
  k_cvt_bf<<<1024, 256, 0, stream>>>(E, E_bf, 262144);
  k_ln<<<1024, 256, 0, stream>>>(x, g1, be1, a_bf);
  k_gemm<0, 128><<<dim3(12, 32), 256, 0, stream>>>(a_bf, Wqkv_t, 4096, 1536, 512,
                                                   b_qkv, nullptr, nullptr, nullptr,
                                                   present, q_bf, k_bf, vt_bf);
  k_attn<<<512, 256, 0, stream>>>(q_bf, k_bf, vt_bf, E_bf, att_bf);
  k_gemm<1, 64><<<dim3(8, 32), 256, 0, stream>>>(att_bf, Wproj_t, 4096, 512, 512,
                                                 b_proj, x, x2, nullptr, nullptr, nullptr,
                                                 nullptr, nullptr);
  k_ln<<<1024, 256, 0, stream>>>(x2, g2, be2, m_bf);
  k_gemm<2, 128><<<dim3(16, 32), 256, 0, stream>>>(m_bf, Wfc1_t, 4096, 2048, 512,
                                                   b_fc1, nullptr, nullptr, h_bf, nullptr,
                                                   nullptr, nullptr, nullptr);
  k_gemm<1, 64><<<dim3(8, 32), 256, 0, stream>>>(h_bf, Wfc2_t, 4096, 512, 2048,
                                                 b_fc2, x2, x_out, nullptr, nullptr, nullptr,
                                                 nullptr, nullptr);
}